// Round 1
// baseline (1460.828 us; speedup 1.0000x reference)
//
#include <hip/hip_runtime.h>

#define C_FEAT 128
#define C_EDGE 32
#define K1 288

typedef __attribute__((ext_vector_type(8))) short bf16x8;
typedef __attribute__((ext_vector_type(4))) float f32x4;

__device__ __forceinline__ short f2bf(float x) {
    union { float f; unsigned u; } v; v.f = x;
    unsigned r = v.u + 0x7fffu + ((v.u >> 16) & 1u);   // RTN-even
    return (short)(r >> 16);
}
__device__ __forceinline__ float b2f(short s) {
    union { float f; unsigned u; } v; v.u = ((unsigned)(unsigned short)s) << 16;
    return v.f;
}
__device__ __forceinline__ bf16x8 cvt8(float4 a, float4 b) {
    bf16x8 r;
    r[0] = f2bf(a.x); r[1] = f2bf(a.y); r[2] = f2bf(a.z); r[3] = f2bf(a.w);
    r[4] = f2bf(b.x); r[5] = f2bf(b.y); r[6] = f2bf(b.z); r[7] = f2bf(b.w);
    return r;
}

// ---------------- weight packing ----------------
// B-fragment layout: wp[((k>>3)*F + f)*8 + (k&7)] -> 8 consecutive k for fixed
// f is one 16B load per lane.
__global__ void prep_w2(const float* __restrict__ We1, const float* __restrict__ We2,
                        short* __restrict__ w1abp, short* __restrict__ w1cp,
                        short* __restrict__ w2p) {
    int idx = blockIdx.x * 256 + threadIdx.x;
    if (idx < 128 * 256) {              // [W1a | W1b]: K=128, F=256
        int k = idx >> 8, f = idx & 255;
        float v = (f < 128) ? We1[k * 128 + f] : We1[(128 + k) * 128 + (f - 128)];
        w1abp[(((k >> 3) * 256 + f) << 3) + (k & 7)] = f2bf(v);
    }
    if (idx < 32 * 128) {               // W1c: K=32, F=128
        int k = idx >> 7, f = idx & 127;
        w1cp[(((k >> 3) * 128 + f) << 3) + (k & 7)] = f2bf(We1[(256 + k) * 128 + f]);
    }
    if (idx < 128 * 128) {              // We2
        int k = idx >> 7, f = idx & 127;
        w2p[(((k >> 3) * 128 + f) << 3) + (k & 7)] = f2bf(We2[k * 128 + f]);
    }
}

// ---------------- counting sort by ej (hist zeroed via memsetAsync) -------
__global__ void k_hist(const int* __restrict__ ej, int* __restrict__ hist, int E) {
    int e = blockIdx.x * 256 + threadIdx.x;
    if (e < E) atomicAdd(&hist[ej[e]], 1);
}
__global__ void k_red(const int* __restrict__ hist, int* __restrict__ part, int N) {
    __shared__ int s[512];
    int t = threadIdx.x, i = blockIdx.x * 512 + t;
    s[t] = i < N ? hist[i] : 0;
    __syncthreads();
    for (int o = 256; o > 0; o >>= 1) {
        if (t < o) s[t] += s[t + o];
        __syncthreads();
    }
    if (t == 0) part[blockIdx.x] = s[0];
}
__global__ void k_scanpart(int* __restrict__ part, int nb) {
    if (threadIdx.x == 0 && blockIdx.x == 0) {
        int a = 0;
        for (int i = 0; i < nb; ++i) { int v = part[i]; part[i] = a; a += v; }
    }
}
__global__ void k_scanblk(const int* __restrict__ hist, const int* __restrict__ part,
                          int* __restrict__ woff, int N) {
    __shared__ int s[512];
    int t = threadIdx.x, i = blockIdx.x * 512 + t;
    int v = i < N ? hist[i] : 0;
    s[t] = v;
    __syncthreads();
    for (int o = 1; o < 512; o <<= 1) {
        int x = (t >= o) ? s[t - o] : 0;
        __syncthreads();
        s[t] += x;
        __syncthreads();
    }
    if (i < N) woff[i] = part[blockIdx.x] + s[t] - v;   // exclusive
}
// permute edges into ej-sorted order; fuse ea gather+bf16 convert.
__global__ void k_perm(const int* __restrict__ ei, const int* __restrict__ ej,
                       const float* __restrict__ ea, int* __restrict__ woff,
                       int* __restrict__ ei_s, int* __restrict__ ej_s,
                       short* __restrict__ ea_s, int E) {
    int e = blockIdx.x * 256 + threadIdx.x;
    if (e < E) {
        int t = ej[e];
        int pos = atomicAdd(&woff[t], 1);
        ei_s[pos] = ei[e];
        ej_s[pos] = t;
        const float4* src = (const float4*)(ea + (size_t)e * C_EDGE);
        short* dst = ea_s + (size_t)pos * C_EDGE;
#pragma unroll
        for (int c = 0; c < 4; ++c) {
            float4 a0 = src[2 * c], a1 = src[2 * c + 1];
            bf16x8 v = cvt8(a0, a1);
            *(bf16x8*)(dst + c * 8) = v;
        }
    }
}

// ---------------- Xab = h @ [W1a|W1b]  (N x 256, bf16) ----------------
__global__ __launch_bounds__(256) void gemm1(const float* __restrict__ h,
                                             const short* __restrict__ w1abp,
                                             short* __restrict__ Xab, int N) {
    const int tid = threadIdx.x, wave = tid >> 6, lane = tid & 63;
    const int l15 = lane & 15, q = lane >> 4;
    const int nbase = blockIdx.x * 64 + wave * 16;
    const int nr = nbase + l15;
    const int nrc = nr < N ? nr : N - 1;
    f32x4 acc[16];
#pragma unroll
    for (int nt = 0; nt < 16; ++nt) acc[nt] = (f32x4){0.f, 0.f, 0.f, 0.f};
#pragma unroll
    for (int c = 0; c < 4; ++c) {
        const float* asrc = h + (size_t)nrc * C_FEAT + c * 32 + q * 8;
        float4 a0 = ((const float4*)asrc)[0];
        float4 a1 = ((const float4*)asrc)[1];
        bf16x8 af = cvt8(a0, a1);
        const short* bb = w1abp + ((c * 4 + q) * 256) * 8;
#pragma unroll
        for (int nt = 0; nt < 16; ++nt) {
            bf16x8 bf = *(const bf16x8*)(bb + (nt * 16 + l15) * 8);
            acc[nt] = __builtin_amdgcn_mfma_f32_16x16x32_bf16(af, bf, acc[nt], 0, 0, 0);
        }
    }
#pragma unroll
    for (int rr = 0; rr < 4; ++rr) {
        int n = nbase + q * 4 + rr;
        if (n < N) {
#pragma unroll
            for (int nt = 0; nt < 16; ++nt) {
                Xab[(size_t)n * 256 + nt * 16 + l15] = f2bf(acc[nt][rr]);
            }
        }
    }
}

// ==================== NEW: relu-sum edge pass (no layer-2 GEMM) ============
// Linearity: sum_e(relu_e @ We2 + be2) = (sum_e relu_e) @ We2 + deg*be2.
// Phase A: z = ea@W1c + be1 via MFMA into 32KB XOR-swizzled LDS (5 blk/CU).
// Phase B: 16 threads/edge (feature-parallel, coalesced 256B row gathers),
//          each 16-thread stream walks 8 ej-sorted edges, run-merged atomics.
#define ZS2 128
__global__ __launch_bounds__(256) void edge_pass2(const short* __restrict__ Xab,
                                                  const short* __restrict__ ea_s,
                                                  const int* __restrict__ ei_s,
                                                  const int* __restrict__ ej_s,
                                                  const short* __restrict__ w1cp,
                                                  const float* __restrict__ be1,
                                                  float* __restrict__ Acc, int E) {
    __shared__ short Z[4][2][16 * ZS2];   // 32768 B exactly -> 5 blocks/CU
    const int tid = threadIdx.x, wave = tid >> 6, lane = tid & 63;
    const int l15 = lane & 15, q = lane >> 4;
    const int base = blockIdx.x * 128 + wave * 32;

    // ---- phase A: z for this wave's 32 edges ----
#pragma unroll
    for (int t = 0; t < 2; ++t) {
        int eg = base + t * 16 + l15;
        int egc = eg < E ? eg : E - 1;
        bf16x8 af = *(const bf16x8*)(ea_s + (size_t)egc * C_EDGE + q * 8);
        f32x4 accP[8];
#pragma unroll
        for (int nt = 0; nt < 8; ++nt) {
            bf16x8 bf = *(const bf16x8*)(w1cp + ((q * C_FEAT + nt * 16 + l15) << 3));
            accP[nt] = __builtin_amdgcn_mfma_f32_16x16x32_bf16(
                af, bf, (f32x4){0.f, 0.f, 0.f, 0.f}, 0, 0, 0);
        }
        short* zw = &Z[wave][t][0];
#pragma unroll
        for (int nt = 0; nt < 8; ++nt) {
            int f = nt * 16 + l15;
            float b = be1[f];
#pragma unroll
            for (int r = 0; r < 4; ++r) {
                int row = q * 4 + r;
                // XOR-swizzle on 16B granule: breaks write-bank collisions and
                // keeps the 8-short read chunk contiguous.
                zw[row * ZS2 + (f ^ ((row & 7) << 3))] = f2bf(accP[nt][r] + b);
            }
        }
    }
    __syncthreads();

    // ---- phase B: gather + relu + run-merged scatter into Acc ----
    const int fg = lane & 15;          // feature group: floats [fg*8, fg*8+8)
    const int es = lane >> 4;          // edge stream (4 per wave)
    const int ebase = base + es * 8;
    float vs[8];
    int cur = -1;
#pragma unroll
    for (int i = 0; i < 8; ++i) {
        int e = ebase + i;
        int ec = e < E ? e : E - 1;
        int ni = ei_s[ec];
        int nj = ej_s[ec];
        bf16x8 xa = *(const bf16x8*)(Xab + (size_t)ni * 256 + fg * 8);
        bf16x8 xb = *(const bf16x8*)(Xab + (size_t)nj * 256 + 128 + fg * 8);
        int eo = es * 8 + i;
        int r = eo & 15;
        bf16x8 zz = *(const bf16x8*)(&Z[wave][eo >> 4][r * ZS2 + ((fg ^ (r & 7)) << 3)]);
        if (e < E) {
            if (nj != cur) {
                if (cur >= 0) {
                    float* dst = Acc + (size_t)cur * C_FEAT + fg * 8;
#pragma unroll
                    for (int j = 0; j < 8; ++j) unsafeAtomicAdd(dst + j, vs[j]);
                }
                cur = nj;
#pragma unroll
                for (int j = 0; j < 8; ++j) vs[j] = 0.f;
            }
#pragma unroll
            for (int j = 0; j < 8; ++j) {
                float v = b2f(xa[j]) + b2f(xb[j]) + b2f(zz[j]);
                vs[j] += v > 0.f ? v : 0.f;
            }
        }
    }
    if (cur >= 0) {
        float* dst = Acc + (size_t)cur * C_FEAT + fg * 8;
#pragma unroll
        for (int j = 0; j < 8; ++j) unsafeAtomicAdd(dst + j, vs[j]);
    }
}

// ---- node finalize: out = prevh + Acc@We2 + deg*be2 (+bias on last step) ----
__global__ __launch_bounds__(256) void node_fin(const float* __restrict__ prevh,
                                                const float* __restrict__ Acc,
                                                const short* __restrict__ w2p,
                                                const float* __restrict__ be2,
                                                const int* __restrict__ deg,
                                                const float* __restrict__ bias,
                                                float* __restrict__ out,
                                                int N, int addBias) {
    const int tid = threadIdx.x, wave = tid >> 6, lane = tid & 63;
    const int l15 = lane & 15, q = lane >> 4;
    const int nbase = blockIdx.x * 64 + wave * 16;
    const int nr = nbase + l15;
    const int nrc = nr < N ? nr : N - 1;
    f32x4 acc[8];
#pragma unroll
    for (int nt = 0; nt < 8; ++nt) acc[nt] = (f32x4){0.f, 0.f, 0.f, 0.f};
#pragma unroll
    for (int c = 0; c < 4; ++c) {
        const float* asrc = Acc + (size_t)nrc * C_FEAT + c * 32 + q * 8;
        float4 a0 = ((const float4*)asrc)[0];
        float4 a1 = ((const float4*)asrc)[1];
        bf16x8 af = cvt8(a0, a1);
        const short* bb = w2p + ((c * 4 + q) * C_FEAT) * 8;
#pragma unroll
        for (int nt = 0; nt < 8; ++nt) {
            bf16x8 bf = *(const bf16x8*)(bb + (nt * 16 + l15) * 8);
            acc[nt] = __builtin_amdgcn_mfma_f32_16x16x32_bf16(af, bf, acc[nt], 0, 0, 0);
        }
    }
    float dv[4];
#pragma unroll
    for (int r = 0; r < 4; ++r) {
        int n = nbase + q * 4 + r;
        dv[r] = n < N ? (float)deg[n] : 0.f;
    }
#pragma unroll
    for (int nt = 0; nt < 8; ++nt) {
        int f = nt * 16 + l15;
        float b2 = be2[f];
        float bi = addBias ? bias[f] : 0.f;
#pragma unroll
        for (int r = 0; r < 4; ++r) {
            int n = nbase + q * 4 + r;
            if (n < N) {
                out[(size_t)n * C_FEAT + f] =
                    prevh[(size_t)n * C_FEAT + f] + acc[nt][r] + dv[r] * b2 + bi;
            }
        }
    }
}

// ==================== previous main path (mid-size fallback) ===============
#define ZSTRIDE 136
__global__ __launch_bounds__(256) void edge_pass(const short* __restrict__ Xab,
                                                 const short* __restrict__ ea_s,
                                                 const int* __restrict__ ei_s,
                                                 const int* __restrict__ ej_s,
                                                 const short* __restrict__ w1cp,
                                                 const float* __restrict__ be1,
                                                 const short* __restrict__ w2p,
                                                 const float* __restrict__ be2,
                                                 float* __restrict__ hdst, int E) {
    __shared__ short Z[4][2][16 * ZSTRIDE];
    const int tid = threadIdx.x, wave = tid >> 6, lane = tid & 63;
    const int l15 = lane & 15, q = lane >> 4;
    const int base = blockIdx.x * 128 + wave * 32;

    int ni[2], nj[2], egc[2];
#pragma unroll
    for (int t = 0; t < 2; ++t) {
        int eg = base + t * 16 + l15;
        egc[t] = eg < E ? eg : E - 1;
        ni[t] = ei_s[egc[t]];
        nj[t] = ej_s[egc[t]];
    }
#pragma unroll
    for (int t = 0; t < 2; ++t) {
        bf16x8 af = *(const bf16x8*)(ea_s + (size_t)egc[t] * C_EDGE + q * 8);
        f32x4 accP[8];
#pragma unroll
        for (int nt = 0; nt < 8; ++nt) {
            bf16x8 bf = *(const bf16x8*)(w1cp + ((q * C_FEAT + nt * 16 + l15) << 3));
            accP[nt] = __builtin_amdgcn_mfma_f32_16x16x32_bf16(
                af, bf, (f32x4){0.f, 0.f, 0.f, 0.f}, 0, 0, 0);
        }
        short* zw = &Z[wave][t][0];
#pragma unroll
        for (int nt = 0; nt < 8; ++nt) {
            int f = nt * 16 + l15;
            float b = be1[f];
#pragma unroll
            for (int r = 0; r < 4; ++r) {
                zw[(q * 4 + r) * ZSTRIDE + f] = f2bf(accP[nt][r] + b);
            }
        }
    }
    __syncthreads();

    f32x4 acc[2][8];
#pragma unroll
    for (int t = 0; t < 2; ++t)
#pragma unroll
        for (int nt = 0; nt < 8; ++nt) acc[t][nt] = (f32x4){0.f, 0.f, 0.f, 0.f};
#pragma unroll
    for (int c = 0; c < 4; ++c) {
        bf16x8 bfr[8];
        const short* bb = w2p + ((c * 4 + q) * C_FEAT) * 8;
#pragma unroll
        for (int nt = 0; nt < 8; ++nt)
            bfr[nt] = *(const bf16x8*)(bb + (nt * 16 + l15) * 8);
#pragma unroll
        for (int t = 0; t < 2; ++t) {
            bf16x8 xa = *(const bf16x8*)(Xab + (size_t)ni[t] * 256 + c * 32 + q * 8);
            bf16x8 xb = *(const bf16x8*)(Xab + (size_t)nj[t] * 256 + 128 + c * 32 + q * 8);
            bf16x8 zz = *(const bf16x8*)(&Z[wave][t][l15 * ZSTRIDE + c * 32 + q * 8]);
            bf16x8 af;
#pragma unroll
            for (int j = 0; j < 8; ++j) {
                float z = b2f(xa[j]) + b2f(xb[j]) + b2f(zz[j]);
                af[j] = f2bf(z > 0.f ? z : 0.f);
            }
#pragma unroll
            for (int nt = 0; nt < 8; ++nt)
                acc[t][nt] = __builtin_amdgcn_mfma_f32_16x16x32_bf16(af, bfr[nt],
                                                                     acc[t][nt], 0, 0, 0);
        }
    }
    float b2v[8];
#pragma unroll
    for (int nt = 0; nt < 8; ++nt) b2v[nt] = be2[nt * 16 + l15];
#pragma unroll
    for (int t = 0; t < 2; ++t) {
        int cur = -1;
        float vs[8];
#pragma unroll
        for (int rr = 0; rr < 4; ++rr) {
            int e = base + t * 16 + q * 4 + rr;
            if (e < E) {
                int tn = ej_s[e];
                if (tn == cur) {
#pragma unroll
                    for (int nt = 0; nt < 8; ++nt) vs[nt] += acc[t][nt][rr] + b2v[nt];
                } else {
                    if (cur >= 0) {
                        float* dst = hdst + (size_t)cur * C_FEAT;
#pragma unroll
                        for (int nt = 0; nt < 8; ++nt)
                            unsafeAtomicAdd(dst + nt * 16 + l15, vs[nt]);
                    }
                    cur = tn;
#pragma unroll
                    for (int nt = 0; nt < 8; ++nt) vs[nt] = acc[t][nt][rr] + b2v[nt];
                }
            }
        }
        if (cur >= 0) {
            float* dst = hdst + (size_t)cur * C_FEAT;
#pragma unroll
            for (int nt = 0; nt < 8; ++nt)
                unsafeAtomicAdd(dst + nt * 16 + l15, vs[nt]);
        }
    }
}

// ---------------- elementwise helpers ----------------
__global__ void copy_f4(const float4* __restrict__ s, float4* __restrict__ d, int n4) {
    int i = blockIdx.x * 256 + threadIdx.x;
    if (i < n4) d[i] = s[i];
}
__global__ void bias_copy(const float4* __restrict__ s, const float* __restrict__ bias,
                          float4* __restrict__ d, int n4) {
    int i = blockIdx.x * 256 + threadIdx.x;
    if (i < n4) {
        float4 v = s[i];
        float4 b = ((const float4*)bias)[i & 31];
        d[i] = make_float4(v.x + b.x, v.y + b.y, v.z + b.z, v.w + b.w);
    }
}

// ================= round-1 fallback path (known-good) =================
__global__ void prep_w_r1(const float* __restrict__ W1, const float* __restrict__ W2,
                          short* __restrict__ w1p, short* __restrict__ w2p) {
    int idx = blockIdx.x * 256 + threadIdx.x;
    if (idx < K1 * C_FEAT) {
        int k = idx >> 7, f = idx & 127;
        w1p[(((k >> 3) * C_FEAT + f) << 3) + (k & 7)] = f2bf(W1[idx]);
    }
    if (idx < C_FEAT * C_FEAT) {
        int k = idx >> 7, f = idx & 127;
        w2p[(((k >> 3) * C_FEAT + f) << 3) + (k & 7)] = f2bf(W2[idx]);
    }
}
__global__ __launch_bounds__(256) void edge_mlp_r1(
    const float* __restrict__ h, float* __restrict__ hdst,
    const int* __restrict__ ei, const int* __restrict__ ej,
    const float* __restrict__ ea,
    const short* __restrict__ w1p, const float* __restrict__ be1,
    const short* __restrict__ w2p, const float* __restrict__ be2, int E) {
    __shared__ short Hs[64][136];
    const int tid = threadIdx.x, wave = tid >> 6, lane = tid & 63;
    const int l15 = lane & 15, q = lane >> 4;
    const int ewave = blockIdx.x * 64 + wave * 16;
    const int eg = ewave + l15;
    const int egc = eg < E ? eg : E - 1;
    const int ni = ei[egc], nj = ej[egc];
    f32x4 acc[8];
#pragma unroll
    for (int nt = 0; nt < 8; ++nt) acc[nt] = (f32x4){0.f, 0.f, 0.f, 0.f};
#pragma unroll
    for (int c = 0; c < 9; ++c) {
        const float* asrc;
        if (c < 4)      asrc = h + (size_t)ni * C_FEAT + c * 32 + q * 8;
        else if (c < 8) asrc = h + (size_t)nj * C_FEAT + (c - 4) * 32 + q * 8;
        else            asrc = ea + (size_t)egc * C_EDGE + q * 8;
        float4 a0 = ((const float4*)asrc)[0];
        float4 a1 = ((const float4*)asrc)[1];
        bf16x8 af = cvt8(a0, a1);
        const short* bb = w1p + ((c * 4 + q) * C_FEAT) * 8;
#pragma unroll
        for (int nt = 0; nt < 8; ++nt) {
            bf16x8 bf = *(const bf16x8*)(bb + (nt * 16 + l15) * 8);
            acc[nt] = __builtin_amdgcn_mfma_f32_16x16x32_bf16(af, bf, acc[nt], 0, 0, 0);
        }
    }
#pragma unroll
    for (int nt = 0; nt < 8; ++nt) {
        int f = nt * 16 + l15;
        float b = be1[f];
#pragma unroll
        for (int r = 0; r < 4; ++r) {
            float v = acc[nt][r] + b;
            Hs[wave * 16 + q * 4 + r][f] = f2bf(v > 0.f ? v : 0.f);
        }
    }
    __syncthreads();
    f32x4 acc2[8];
#pragma unroll
    for (int nt = 0; nt < 8; ++nt) acc2[nt] = (f32x4){0.f, 0.f, 0.f, 0.f};
#pragma unroll
    for (int c = 0; c < 4; ++c) {
        bf16x8 af = *(const bf16x8*)(&Hs[wave * 16 + l15][c * 32 + q * 8]);
        const short* bb = w2p + ((c * 4 + q) * C_FEAT) * 8;
#pragma unroll
        for (int nt = 0; nt < 8; ++nt) {
            bf16x8 bf = *(const bf16x8*)(bb + (nt * 16 + l15) * 8);
            acc2[nt] = __builtin_amdgcn_mfma_f32_16x16x32_bf16(af, bf, acc2[nt], 0, 0, 0);
        }
    }
    float b2v[8];
#pragma unroll
    for (int nt = 0; nt < 8; ++nt) b2v[nt] = be2[nt * 16 + l15];
#pragma unroll
    for (int r = 0; r < 4; ++r) {
        int e = ewave + q * 4 + r;
        if (e < E) {
            int tn = ej[e];
            float* dst = hdst + (size_t)tn * C_FEAT;
#pragma unroll
            for (int nt = 0; nt < 8; ++nt)
                unsafeAtomicAdd(dst + nt * 16 + l15, acc2[nt][r] + b2v[nt]);
        }
    }
}

static inline size_t al256(size_t x) { return (x + 255) & ~(size_t)255; }

extern "C" void kernel_launch(void* const* d_in, const int* in_sizes, int n_in,
                              void* d_out, int out_size, void* d_ws, size_t ws_size,
                              hipStream_t stream) {
    const float* x    = (const float*)d_in[0];
    const int*   eidx = (const int*)  d_in[1];
    const float* ea   = (const float*)d_in[2];
    const float* We1  = (const float*)d_in[3];
    const float* be1  = (const float*)d_in[4];
    const float* We2  = (const float*)d_in[5];
    const float* be2  = (const float*)d_in[6];
    const float* bias = (const float*)d_in[7];
    float* out = (float*)d_out;

    const int E = in_sizes[1] / 2;
    const int N = in_sizes[0] / C_FEAT;
    const int* ei = eidx;
    const int* ej = eidx + E;

    const int n4 = N * C_FEAT / 4;
    const int cb = (n4 + 255) / 256;
    const int eb2 = (E + 127) / 128;
    const int nb64 = (N + 63) / 64;

    // ---- workspace layout ----
    size_t off = 0;
    size_t o_w1abp = off; off = al256(off + (size_t)128 * 256 * 2);
    size_t o_w1cp  = off; off = al256(off + (size_t)32 * 128 * 2);
    size_t o_w2p   = off; off = al256(off + (size_t)128 * 128 * 2);
    size_t o_hist  = off; off = al256(off + (size_t)N * 4);
    size_t o_part  = off; off = al256(off + (size_t)4096);
    size_t o_woff  = off; off = al256(off + (size_t)N * 4);
    size_t o_eis   = off; off = al256(off + (size_t)E * 4);
    size_t o_ejs   = off; off = al256(off + (size_t)E * 4);
    size_t o_eas   = off; off = al256(off + (size_t)E * C_EDGE * 2);
    size_t o_xab   = off; off = al256(off + (size_t)N * 256 * 2);
    const size_t need_old = off;
    size_t o_acc   = off; off = al256(off + (size_t)N * C_FEAT * 4);
    const size_t need_new = off;

    if (ws_size >= need_old) {
        char* ws = (char*)d_ws;
        short* w1abp = (short*)(ws + o_w1abp);
        short* w1cp  = (short*)(ws + o_w1cp);
        short* w2p   = (short*)(ws + o_w2p);
        int* hist    = (int*)(ws + o_hist);
        int* part    = (int*)(ws + o_part);
        int* woff    = (int*)(ws + o_woff);
        int* ei_s    = (int*)(ws + o_eis);
        int* ej_s    = (int*)(ws + o_ejs);
        short* ea_s  = (short*)(ws + o_eas);
        short* Xab   = (short*)(ws + o_xab);

        const int nbScan = (N + 511) / 512;

        prep_w2<<<128, 256, 0, stream>>>(We1, We2, w1abp, w1cp, w2p);
        // counting sort by ej (+ fused ea permute/convert); hist survives as deg
        hipMemsetAsync(hist, 0, (size_t)N * 4, stream);
        k_hist<<<(E + 255) / 256, 256, 0, stream>>>(ej, hist, E);
        k_red<<<nbScan, 512, 0, stream>>>(hist, part, N);
        k_scanpart<<<1, 64, 0, stream>>>(part, nbScan);
        k_scanblk<<<nbScan, 512, 0, stream>>>(hist, part, woff, N);
        k_perm<<<(E + 255) / 256, 256, 0, stream>>>(ei, ej, ea, woff, ei_s, ej_s, ea_s, E);

        if (ws_size >= need_new) {
            float* Acc = (float*)(ws + o_acc);
            // step 1: out = x + (sum relu)@We2 + deg*be2
            gemm1<<<nb64, 256, 0, stream>>>(x, w1abp, Xab, N);
            hipMemsetAsync(Acc, 0, (size_t)N * C_FEAT * 4, stream);
            edge_pass2<<<eb2, 256, 0, stream>>>(Xab, ea_s, ei_s, ej_s, w1cp, be1, Acc, E);
            node_fin<<<nb64, 256, 0, stream>>>(x, Acc, w2p, be2, hist, bias, out, N, 0);
            // step 2: out = h1 + (sum relu)@We2 + deg*be2 + bias
            gemm1<<<nb64, 256, 0, stream>>>(out, w1abp, Xab, N);
            hipMemsetAsync(Acc, 0, (size_t)N * C_FEAT * 4, stream);
            edge_pass2<<<eb2, 256, 0, stream>>>(Xab, ea_s, ei_s, ej_s, w1cp, be1, Acc, E);
            node_fin<<<nb64, 256, 0, stream>>>(out, Acc, w2p, be2, hist, bias, out, N, 1);
        } else {
            // previous main path
            gemm1<<<nb64, 256, 0, stream>>>(x, w1abp, Xab, N);
            copy_f4<<<cb, 256, 0, stream>>>((const float4*)x, (float4*)out, n4);
            edge_pass<<<eb2, 256, 0, stream>>>(Xab, ea_s, ei_s, ej_s, w1cp, be1, w2p, be2, out, E);
            gemm1<<<nb64, 256, 0, stream>>>(out, w1abp, Xab, N);
            bias_copy<<<cb, 256, 0, stream>>>((const float4*)out, bias, (float4*)out, n4);
            edge_pass<<<eb2, 256, 0, stream>>>(Xab, ea_s, ei_s, ej_s, w1cp, be1, w2p, be2, out, E);
        }
    } else {
        // round-1 known-good fallback
        const int eb = (E + 63) / 64;
        float* bufA = (float*)d_ws;
        short* w1p  = (short*)((char*)d_ws + (size_t)N * C_FEAT * sizeof(float));
        short* w2p  = w1p + K1 * C_FEAT;
        prep_w_r1<<<144, 256, 0, stream>>>(We1, We2, w1p, w2p);
        copy_f4<<<cb, 256, 0, stream>>>((const float4*)x, (float4*)bufA, n4);
        edge_mlp_r1<<<eb, 256, 0, stream>>>(x, bufA, ei, ej, ea, w1p, be1, w2p, be2, E);
        bias_copy<<<cb, 256, 0, stream>>>((const float4*)bufA, bias, (float4*)out, n4);
        edge_mlp_r1<<<eb, 256, 0, stream>>>(bufA, out, ei, ej, ea, w1p, be1, w2p, be2, E);
    }
}

// Round 2
// 567.438 us; speedup vs baseline: 2.5744x; 2.5744x over previous
//
#include <hip/hip_runtime.h>

#define C_FEAT 128
#define C_EDGE 32
#define K1 288

typedef __attribute__((ext_vector_type(8))) short bf16x8;
typedef __attribute__((ext_vector_type(4))) float f32x4;

__device__ __forceinline__ short f2bf(float x) {
    union { float f; unsigned u; } v; v.f = x;
    unsigned r = v.u + 0x7fffu + ((v.u >> 16) & 1u);   // RTN-even
    return (short)(r >> 16);
}
__device__ __forceinline__ float b2f(short s) {
    union { float f; unsigned u; } v; v.u = ((unsigned)(unsigned short)s) << 16;
    return v.f;
}
__device__ __forceinline__ bf16x8 cvt8(float4 a, float4 b) {
    bf16x8 r;
    r[0] = f2bf(a.x); r[1] = f2bf(a.y); r[2] = f2bf(a.z); r[3] = f2bf(a.w);
    r[4] = f2bf(b.x); r[5] = f2bf(b.y); r[6] = f2bf(b.z); r[7] = f2bf(b.w);
    return r;
}

// ---------------- weight packing ----------------
// B-fragment layout: wp[((k>>3)*F + f)*8 + (k&7)] -> 8 consecutive k for fixed
// f is one 16B load per lane.
__global__ void prep_w2(const float* __restrict__ We1, const float* __restrict__ We2,
                        short* __restrict__ w1abp, short* __restrict__ w1cp,
                        short* __restrict__ w2p) {
    int idx = blockIdx.x * 256 + threadIdx.x;
    if (idx < 128 * 256) {              // [W1a | W1b]: K=128, F=256
        int k = idx >> 8, f = idx & 255;
        float v = (f < 128) ? We1[k * 128 + f] : We1[(128 + k) * 128 + (f - 128)];
        w1abp[(((k >> 3) * 256 + f) << 3) + (k & 7)] = f2bf(v);
    }
    if (idx < 32 * 128) {               // W1c: K=32, F=128
        int k = idx >> 7, f = idx & 127;
        w1cp[(((k >> 3) * 128 + f) << 3) + (k & 7)] = f2bf(We1[(256 + k) * 128 + f]);
    }
    if (idx < 128 * 128) {              // We2
        int k = idx >> 7, f = idx & 127;
        w2p[(((k >> 3) * 128 + f) << 3) + (k & 7)] = f2bf(We2[k * 128 + f]);
    }
}

// ---------------- counting sort by ej (hist zeroed via memsetAsync) -------
__global__ void k_hist(const int* __restrict__ ej, int* __restrict__ hist, int E) {
    int e = blockIdx.x * 256 + threadIdx.x;
    if (e < E) atomicAdd(&hist[ej[e]], 1);
}
__global__ void k_red(const int* __restrict__ hist, int* __restrict__ part, int N) {
    __shared__ int s[512];
    int t = threadIdx.x, i = blockIdx.x * 512 + t;
    s[t] = i < N ? hist[i] : 0;
    __syncthreads();
    for (int o = 256; o > 0; o >>= 1) {
        if (t < o) s[t] += s[t + o];
        __syncthreads();
    }
    if (t == 0) part[blockIdx.x] = s[0];
}
__global__ void k_scanpart(int* __restrict__ part, int nb) {
    if (threadIdx.x == 0 && blockIdx.x == 0) {
        int a = 0;
        for (int i = 0; i < nb; ++i) { int v = part[i]; part[i] = a; a += v; }
    }
}
__global__ void k_scanblk(const int* __restrict__ hist, const int* __restrict__ part,
                          int* __restrict__ woff, int N) {
    __shared__ int s[512];
    int t = threadIdx.x, i = blockIdx.x * 512 + t;
    int v = i < N ? hist[i] : 0;
    s[t] = v;
    __syncthreads();
    for (int o = 1; o < 512; o <<= 1) {
        int x = (t >= o) ? s[t - o] : 0;
        __syncthreads();
        s[t] += x;
        __syncthreads();
    }
    if (i < N) woff[i] = part[blockIdx.x] + s[t] - v;   // exclusive
}
// permute edges into ej-sorted order; fuse ea gather+bf16 convert.
__global__ void k_perm(const int* __restrict__ ei, const int* __restrict__ ej,
                       const float* __restrict__ ea, int* __restrict__ woff,
                       int* __restrict__ ei_s, int* __restrict__ ej_s,
                       short* __restrict__ ea_s, int E) {
    int e = blockIdx.x * 256 + threadIdx.x;
    if (e < E) {
        int t = ej[e];
        int pos = atomicAdd(&woff[t], 1);
        ei_s[pos] = ei[e];
        ej_s[pos] = t;
        const float4* src = (const float4*)(ea + (size_t)e * C_EDGE);
        short* dst = ea_s + (size_t)pos * C_EDGE;
#pragma unroll
        for (int c = 0; c < 4; ++c) {
            float4 a0 = src[2 * c], a1 = src[2 * c + 1];
            bf16x8 v = cvt8(a0, a1);
            *(bf16x8*)(dst + c * 8) = v;
        }
    }
}

// ---------------- Xab = h @ [W1a|W1b]  (N x 256, bf16) ----------------
__global__ __launch_bounds__(256) void gemm1(const float* __restrict__ h,
                                             const short* __restrict__ w1abp,
                                             short* __restrict__ Xab, int N) {
    const int tid = threadIdx.x, wave = tid >> 6, lane = tid & 63;
    const int l15 = lane & 15, q = lane >> 4;
    const int nbase = blockIdx.x * 64 + wave * 16;
    const int nr = nbase + l15;
    const int nrc = nr < N ? nr : N - 1;
    f32x4 acc[16];
#pragma unroll
    for (int nt = 0; nt < 16; ++nt) acc[nt] = (f32x4){0.f, 0.f, 0.f, 0.f};
#pragma unroll
    for (int c = 0; c < 4; ++c) {
        const float* asrc = h + (size_t)nrc * C_FEAT + c * 32 + q * 8;
        float4 a0 = ((const float4*)asrc)[0];
        float4 a1 = ((const float4*)asrc)[1];
        bf16x8 af = cvt8(a0, a1);
        const short* bb = w1abp + ((c * 4 + q) * 256) * 8;
#pragma unroll
        for (int nt = 0; nt < 16; ++nt) {
            bf16x8 bf = *(const bf16x8*)(bb + (nt * 16 + l15) * 8);
            acc[nt] = __builtin_amdgcn_mfma_f32_16x16x32_bf16(af, bf, acc[nt], 0, 0, 0);
        }
    }
#pragma unroll
    for (int rr = 0; rr < 4; ++rr) {
        int n = nbase + q * 4 + rr;
        if (n < N) {
#pragma unroll
            for (int nt = 0; nt < 16; ++nt) {
                Xab[(size_t)n * 256 + nt * 16 + l15] = f2bf(acc[nt][rr]);
            }
        }
    }
}

// ==================== relu-sum edge pass (no layer-2 GEMM) ================
// Linearity: sum_e(relu_e @ We2 + be2) = (sum_e relu_e) @ We2 + deg*be2.
// Phase A: z = ea@W1c + be1 via MFMA into XOR-swizzled LDS.
// Phase B: 16 threads/edge (feature-parallel, coalesced 256B row gathers),
//          each 16-thread stream walks 8 ej-sorted edges, run-merged scatter.
// FLUSH FIX (r1 post-mortem): atomics write through to HBM at ~32B sector
// granularity and only merge lanes contiguous WITHIN one instruction. So the
// flush transposes vs[] through per-stream LDS scratch: atomic instr j then
// covers dst + j*16 + fg -> 16 consecutive dwords = one full 64B line.
#define ZS2 128
__global__ __launch_bounds__(256) void edge_pass2(const short* __restrict__ Xab,
                                                  const short* __restrict__ ea_s,
                                                  const int* __restrict__ ei_s,
                                                  const int* __restrict__ ej_s,
                                                  const short* __restrict__ w1cp,
                                                  const float* __restrict__ be1,
                                                  float* __restrict__ Acc, int E) {
    __shared__ short Z[4][2][16 * ZS2];   // 32 KB
    __shared__ float S[4][4][128];        // 8 KB flush-transpose scratch
    const int tid = threadIdx.x, wave = tid >> 6, lane = tid & 63;
    const int l15 = lane & 15, q = lane >> 4;
    const int base = blockIdx.x * 128 + wave * 32;

    // ---- phase A: z for this wave's 32 edges ----
#pragma unroll
    for (int t = 0; t < 2; ++t) {
        int eg = base + t * 16 + l15;
        int egc = eg < E ? eg : E - 1;
        bf16x8 af = *(const bf16x8*)(ea_s + (size_t)egc * C_EDGE + q * 8);
        f32x4 accP[8];
#pragma unroll
        for (int nt = 0; nt < 8; ++nt) {
            bf16x8 bf = *(const bf16x8*)(w1cp + ((q * C_FEAT + nt * 16 + l15) << 3));
            accP[nt] = __builtin_amdgcn_mfma_f32_16x16x32_bf16(
                af, bf, (f32x4){0.f, 0.f, 0.f, 0.f}, 0, 0, 0);
        }
        short* zw = &Z[wave][t][0];
#pragma unroll
        for (int nt = 0; nt < 8; ++nt) {
            int f = nt * 16 + l15;
            float b = be1[f];
#pragma unroll
            for (int r = 0; r < 4; ++r) {
                int row = q * 4 + r;
                // XOR-swizzle on 16B granule keeps the 8-short read contiguous.
                zw[row * ZS2 + (f ^ ((row & 7) << 3))] = f2bf(accP[nt][r] + b);
            }
        }
    }
    __syncthreads();

    // ---- phase B: gather + relu + run-merged line-coalesced scatter ----
    const int fg = lane & 15;          // feature group: floats [fg*8, fg*8+8)
    const int es = lane >> 4;          // edge stream (4 per wave)
    const int ebase = base + es * 8;
    float* scr = &S[wave][es][0];
    float vs[8];
    int cur = -1;

#pragma unroll
    for (int i = 0; i < 8; ++i) {
        int e = ebase + i;
        int ec = e < E ? e : E - 1;
        int ni = ei_s[ec];
        int nj = ej_s[ec];
        bf16x8 xa = *(const bf16x8*)(Xab + (size_t)ni * 256 + fg * 8);
        bf16x8 xb = *(const bf16x8*)(Xab + (size_t)nj * 256 + 128 + fg * 8);
        int eo = es * 8 + i;
        int r = eo & 15;
        bf16x8 zz = *(const bf16x8*)(&Z[wave][eo >> 4][r * ZS2 + ((fg ^ (r & 7)) << 3)]);
        if (e < E) {
            if (nj != cur) {
                if (cur >= 0) {
                    // transpose through LDS, then full-line atomics
                    *(f32x4*)(scr + fg * 8)     = (f32x4){vs[0], vs[1], vs[2], vs[3]};
                    *(f32x4*)(scr + fg * 8 + 4) = (f32x4){vs[4], vs[5], vs[6], vs[7]};
                    __builtin_amdgcn_wave_barrier();
                    float* dst = Acc + (size_t)cur * C_FEAT;
#pragma unroll
                    for (int j = 0; j < 8; ++j)
                        unsafeAtomicAdd(dst + j * 16 + fg, scr[j * 16 + fg]);
                    __builtin_amdgcn_wave_barrier();
                }
                cur = nj;
#pragma unroll
                for (int j = 0; j < 8; ++j) vs[j] = 0.f;
            }
#pragma unroll
            for (int j = 0; j < 8; ++j) {
                float v = b2f(xa[j]) + b2f(xb[j]) + b2f(zz[j]);
                vs[j] += v > 0.f ? v : 0.f;
            }
        }
    }
    if (cur >= 0) {
        *(f32x4*)(scr + fg * 8)     = (f32x4){vs[0], vs[1], vs[2], vs[3]};
        *(f32x4*)(scr + fg * 8 + 4) = (f32x4){vs[4], vs[5], vs[6], vs[7]};
        __builtin_amdgcn_wave_barrier();
        float* dst = Acc + (size_t)cur * C_FEAT;
#pragma unroll
        for (int j = 0; j < 8; ++j)
            unsafeAtomicAdd(dst + j * 16 + fg, scr[j * 16 + fg]);
    }
}

// ---- node finalize: out = prevh + Acc@We2 + deg*be2 (+bias on last step) ----
__global__ __launch_bounds__(256) void node_fin(const float* __restrict__ prevh,
                                                const float* __restrict__ Acc,
                                                const short* __restrict__ w2p,
                                                const float* __restrict__ be2,
                                                const int* __restrict__ deg,
                                                const float* __restrict__ bias,
                                                float* __restrict__ out,
                                                int N, int addBias) {
    const int tid = threadIdx.x, wave = tid >> 6, lane = tid & 63;
    const int l15 = lane & 15, q = lane >> 4;
    const int nbase = blockIdx.x * 64 + wave * 16;
    const int nr = nbase + l15;
    const int nrc = nr < N ? nr : N - 1;
    f32x4 acc[8];
#pragma unroll
    for (int nt = 0; nt < 8; ++nt) acc[nt] = (f32x4){0.f, 0.f, 0.f, 0.f};
#pragma unroll
    for (int c = 0; c < 4; ++c) {
        const float* asrc = Acc + (size_t)nrc * C_FEAT + c * 32 + q * 8;
        float4 a0 = ((const float4*)asrc)[0];
        float4 a1 = ((const float4*)asrc)[1];
        bf16x8 af = cvt8(a0, a1);
        const short* bb = w2p + ((c * 4 + q) * C_FEAT) * 8;
#pragma unroll
        for (int nt = 0; nt < 8; ++nt) {
            bf16x8 bf = *(const bf16x8*)(bb + (nt * 16 + l15) * 8);
            acc[nt] = __builtin_amdgcn_mfma_f32_16x16x32_bf16(af, bf, acc[nt], 0, 0, 0);
        }
    }
    float dv[4];
#pragma unroll
    for (int r = 0; r < 4; ++r) {
        int n = nbase + q * 4 + r;
        dv[r] = n < N ? (float)deg[n] : 0.f;
    }
#pragma unroll
    for (int nt = 0; nt < 8; ++nt) {
        int f = nt * 16 + l15;
        float b2 = be2[f];
        float bi = addBias ? bias[f] : 0.f;
#pragma unroll
        for (int r = 0; r < 4; ++r) {
            int n = nbase + q * 4 + r;
            if (n < N) {
                out[(size_t)n * C_FEAT + f] =
                    prevh[(size_t)n * C_FEAT + f] + acc[nt][r] + dv[r] * b2 + bi;
            }
        }
    }
}

// ==================== previous main path (mid-size fallback) ===============
#define ZSTRIDE 136
__global__ __launch_bounds__(256) void edge_pass(const short* __restrict__ Xab,
                                                 const short* __restrict__ ea_s,
                                                 const int* __restrict__ ei_s,
                                                 const int* __restrict__ ej_s,
                                                 const short* __restrict__ w1cp,
                                                 const float* __restrict__ be1,
                                                 const short* __restrict__ w2p,
                                                 const float* __restrict__ be2,
                                                 float* __restrict__ hdst, int E) {
    __shared__ short Z[4][2][16 * ZSTRIDE];
    const int tid = threadIdx.x, wave = tid >> 6, lane = tid & 63;
    const int l15 = lane & 15, q = lane >> 4;
    const int base = blockIdx.x * 128 + wave * 32;

    int ni[2], nj[2], egc[2];
#pragma unroll
    for (int t = 0; t < 2; ++t) {
        int eg = base + t * 16 + l15;
        egc[t] = eg < E ? eg : E - 1;
        ni[t] = ei_s[egc[t]];
        nj[t] = ej_s[egc[t]];
    }
#pragma unroll
    for (int t = 0; t < 2; ++t) {
        bf16x8 af = *(const bf16x8*)(ea_s + (size_t)egc[t] * C_EDGE + q * 8);
        f32x4 accP[8];
#pragma unroll
        for (int nt = 0; nt < 8; ++nt) {
            bf16x8 bf = *(const bf16x8*)(w1cp + ((q * C_FEAT + nt * 16 + l15) << 3));
            accP[nt] = __builtin_amdgcn_mfma_f32_16x16x32_bf16(
                af, bf, (f32x4){0.f, 0.f, 0.f, 0.f}, 0, 0, 0);
        }
        short* zw = &Z[wave][t][0];
#pragma unroll
        for (int nt = 0; nt < 8; ++nt) {
            int f = nt * 16 + l15;
            float b = be1[f];
#pragma unroll
            for (int r = 0; r < 4; ++r) {
                zw[(q * 4 + r) * ZSTRIDE + f] = f2bf(accP[nt][r] + b);
            }
        }
    }
    __syncthreads();

    f32x4 acc[2][8];
#pragma unroll
    for (int t = 0; t < 2; ++t)
#pragma unroll
        for (int nt = 0; nt < 8; ++nt) acc[t][nt] = (f32x4){0.f, 0.f, 0.f, 0.f};
#pragma unroll
    for (int c = 0; c < 4; ++c) {
        bf16x8 bfr[8];
        const short* bb = w2p + ((c * 4 + q) * C_FEAT) * 8;
#pragma unroll
        for (int nt = 0; nt < 8; ++nt)
            bfr[nt] = *(const bf16x8*)(bb + (nt * 16 + l15) * 8);
#pragma unroll
        for (int t = 0; t < 2; ++t) {
            bf16x8 xa = *(const bf16x8*)(Xab + (size_t)ni[t] * 256 + c * 32 + q * 8);
            bf16x8 xb = *(const bf16x8*)(Xab + (size_t)nj[t] * 256 + 128 + c * 32 + q * 8);
            bf16x8 zz = *(const bf16x8*)(&Z[wave][t][l15 * ZSTRIDE + c * 32 + q * 8]);
            bf16x8 af;
#pragma unroll
            for (int j = 0; j < 8; ++j) {
                float z = b2f(xa[j]) + b2f(xb[j]) + b2f(zz[j]);
                af[j] = f2bf(z > 0.f ? z : 0.f);
            }
#pragma unroll
            for (int nt = 0; nt < 8; ++nt)
                acc[t][nt] = __builtin_amdgcn_mfma_f32_16x16x32_bf16(af, bfr[nt],
                                                                     acc[t][nt], 0, 0, 0);
        }
    }
    float b2v[8];
#pragma unroll
    for (int nt = 0; nt < 8; ++nt) b2v[nt] = be2[nt * 16 + l15];
#pragma unroll
    for (int t = 0; t < 2; ++t) {
        int cur = -1;
        float vs[8];
#pragma unroll
        for (int rr = 0; rr < 4; ++rr) {
            int e = base + t * 16 + q * 4 + rr;
            if (e < E) {
                int tn = ej_s[e];
                if (tn == cur) {
#pragma unroll
                    for (int nt = 0; nt < 8; ++nt) vs[nt] += acc[t][nt][rr] + b2v[nt];
                } else {
                    if (cur >= 0) {
                        float* dst = hdst + (size_t)cur * C_FEAT;
#pragma unroll
                        for (int nt = 0; nt < 8; ++nt)
                            unsafeAtomicAdd(dst + nt * 16 + l15, vs[nt]);
                    }
                    cur = tn;
#pragma unroll
                    for (int nt = 0; nt < 8; ++nt) vs[nt] = acc[t][nt][rr] + b2v[nt];
                }
            }
        }
        if (cur >= 0) {
            float* dst = hdst + (size_t)cur * C_FEAT;
#pragma unroll
            for (int nt = 0; nt < 8; ++nt)
                unsafeAtomicAdd(dst + nt * 16 + l15, vs[nt]);
        }
    }
}

// ---------------- elementwise helpers ----------------
__global__ void copy_f4(const float4* __restrict__ s, float4* __restrict__ d, int n4) {
    int i = blockIdx.x * 256 + threadIdx.x;
    if (i < n4) d[i] = s[i];
}
__global__ void bias_copy(const float4* __restrict__ s, const float* __restrict__ bias,
                          float4* __restrict__ d, int n4) {
    int i = blockIdx.x * 256 + threadIdx.x;
    if (i < n4) {
        float4 v = s[i];
        float4 b = ((const float4*)bias)[i & 31];
        d[i] = make_float4(v.x + b.x, v.y + b.y, v.z + b.z, v.w + b.w);
    }
}

// ================= round-1 fallback path (known-good) =================
__global__ void prep_w_r1(const float* __restrict__ W1, const float* __restrict__ W2,
                          short* __restrict__ w1p, short* __restrict__ w2p) {
    int idx = blockIdx.x * 256 + threadIdx.x;
    if (idx < K1 * C_FEAT) {
        int k = idx >> 7, f = idx & 127;
        w1p[(((k >> 3) * C_FEAT + f) << 3) + (k & 7)] = f2bf(W1[idx]);
    }
    if (idx < C_FEAT * C_FEAT) {
        int k = idx >> 7, f = idx & 127;
        w2p[(((k >> 3) * C_FEAT + f) << 3) + (k & 7)] = f2bf(W2[idx]);
    }
}
__global__ __launch_bounds__(256) void edge_mlp_r1(
    const float* __restrict__ h, float* __restrict__ hdst,
    const int* __restrict__ ei, const int* __restrict__ ej,
    const float* __restrict__ ea,
    const short* __restrict__ w1p, const float* __restrict__ be1,
    const short* __restrict__ w2p, const float* __restrict__ be2, int E) {
    __shared__ short Hs[64][136];
    const int tid = threadIdx.x, wave = tid >> 6, lane = tid & 63;
    const int l15 = lane & 15, q = lane >> 4;
    const int ewave = blockIdx.x * 64 + wave * 16;
    const int eg = ewave + l15;
    const int egc = eg < E ? eg : E - 1;
    const int ni = ei[egc], nj = ej[egc];
    f32x4 acc[8];
#pragma unroll
    for (int nt = 0; nt < 8; ++nt) acc[nt] = (f32x4){0.f, 0.f, 0.f, 0.f};
#pragma unroll
    for (int c = 0; c < 9; ++c) {
        const float* asrc;
        if (c < 4)      asrc = h + (size_t)ni * C_FEAT + c * 32 + q * 8;
        else if (c < 8) asrc = h + (size_t)nj * C_FEAT + (c - 4) * 32 + q * 8;
        else            asrc = ea + (size_t)egc * C_EDGE + q * 8;
        float4 a0 = ((const float4*)asrc)[0];
        float4 a1 = ((const float4*)asrc)[1];
        bf16x8 af = cvt8(a0, a1);
        const short* bb = w1p + ((c * 4 + q) * C_FEAT) * 8;
#pragma unroll
        for (int nt = 0; nt < 8; ++nt) {
            bf16x8 bf = *(const bf16x8*)(bb + (nt * 16 + l15) * 8);
            acc[nt] = __builtin_amdgcn_mfma_f32_16x16x32_bf16(af, bf, acc[nt], 0, 0, 0);
        }
    }
#pragma unroll
    for (int nt = 0; nt < 8; ++nt) {
        int f = nt * 16 + l15;
        float b = be1[f];
#pragma unroll
        for (int r = 0; r < 4; ++r) {
            float v = acc[nt][r] + b;
            Hs[wave * 16 + q * 4 + r][f] = f2bf(v > 0.f ? v : 0.f);
        }
    }
    __syncthreads();
    f32x4 acc2[8];
#pragma unroll
    for (int nt = 0; nt < 8; ++nt) acc2[nt] = (f32x4){0.f, 0.f, 0.f, 0.f};
#pragma unroll
    for (int c = 0; c < 4; ++c) {
        bf16x8 af = *(const bf16x8*)(&Hs[wave * 16 + l15][c * 32 + q * 8]);
        const short* bb = w2p + ((c * 4 + q) * C_FEAT) * 8;
#pragma unroll
        for (int nt = 0; nt < 8; ++nt) {
            bf16x8 bf = *(const bf16x8*)(bb + (nt * 16 + l15) * 8);
            acc2[nt] = __builtin_amdgcn_mfma_f32_16x16x32_bf16(af, bf, acc2[nt], 0, 0, 0);
        }
    }
    float b2v[8];
#pragma unroll
    for (int nt = 0; nt < 8; ++nt) b2v[nt] = be2[nt * 16 + l15];
#pragma unroll
    for (int r = 0; r < 4; ++r) {
        int e = ewave + q * 4 + r;
        if (e < E) {
            int tn = ej[e];
            float* dst = hdst + (size_t)tn * C_FEAT;
#pragma unroll
            for (int nt = 0; nt < 8; ++nt)
                unsafeAtomicAdd(dst + nt * 16 + l15, acc2[nt][r] + b2v[nt]);
        }
    }
}

static inline size_t al256(size_t x) { return (x + 255) & ~(size_t)255; }

extern "C" void kernel_launch(void* const* d_in, const int* in_sizes, int n_in,
                              void* d_out, int out_size, void* d_ws, size_t ws_size,
                              hipStream_t stream) {
    const float* x    = (const float*)d_in[0];
    const int*   eidx = (const int*)  d_in[1];
    const float* ea   = (const float*)d_in[2];
    const float* We1  = (const float*)d_in[3];
    const float* be1  = (const float*)d_in[4];
    const float* We2  = (const float*)d_in[5];
    const float* be2  = (const float*)d_in[6];
    const float* bias = (const float*)d_in[7];
    float* out = (float*)d_out;

    const int E = in_sizes[1] / 2;
    const int N = in_sizes[0] / C_FEAT;
    const int* ei = eidx;
    const int* ej = eidx + E;

    const int n4 = N * C_FEAT / 4;
    const int cb = (n4 + 255) / 256;
    const int eb2 = (E + 127) / 128;
    const int nb64 = (N + 63) / 64;

    // ---- workspace layout ----
    size_t off = 0;
    size_t o_w1abp = off; off = al256(off + (size_t)128 * 256 * 2);
    size_t o_w1cp  = off; off = al256(off + (size_t)32 * 128 * 2);
    size_t o_w2p   = off; off = al256(off + (size_t)128 * 128 * 2);
    size_t o_hist  = off; off = al256(off + (size_t)N * 4);
    size_t o_part  = off; off = al256(off + (size_t)4096);
    size_t o_woff  = off; off = al256(off + (size_t)N * 4);
    size_t o_eis   = off; off = al256(off + (size_t)E * 4);
    size_t o_ejs   = off; off = al256(off + (size_t)E * 4);
    size_t o_eas   = off; off = al256(off + (size_t)E * C_EDGE * 2);
    size_t o_xab   = off; off = al256(off + (size_t)N * 256 * 2);
    const size_t need_old = off;
    size_t o_acc   = off; off = al256(off + (size_t)N * C_FEAT * 4);
    const size_t need_new = off;

    if (ws_size >= need_old) {
        char* ws = (char*)d_ws;
        short* w1abp = (short*)(ws + o_w1abp);
        short* w1cp  = (short*)(ws + o_w1cp);
        short* w2p   = (short*)(ws + o_w2p);
        int* hist    = (int*)(ws + o_hist);
        int* part    = (int*)(ws + o_part);
        int* woff    = (int*)(ws + o_woff);
        int* ei_s    = (int*)(ws + o_eis);
        int* ej_s    = (int*)(ws + o_ejs);
        short* ea_s  = (short*)(ws + o_eas);
        short* Xab   = (short*)(ws + o_xab);

        const int nbScan = (N + 511) / 512;

        prep_w2<<<128, 256, 0, stream>>>(We1, We2, w1abp, w1cp, w2p);
        // counting sort by ej (+ fused ea permute/convert); hist survives as deg
        hipMemsetAsync(hist, 0, (size_t)N * 4, stream);
        k_hist<<<(E + 255) / 256, 256, 0, stream>>>(ej, hist, E);
        k_red<<<nbScan, 512, 0, stream>>>(hist, part, N);
        k_scanpart<<<1, 64, 0, stream>>>(part, nbScan);
        k_scanblk<<<nbScan, 512, 0, stream>>>(hist, part, woff, N);
        k_perm<<<(E + 255) / 256, 256, 0, stream>>>(ei, ej, ea, woff, ei_s, ej_s, ea_s, E);

        if (ws_size >= need_new) {
            float* Acc = (float*)(ws + o_acc);
            // step 1: out = x + (sum relu)@We2 + deg*be2
            gemm1<<<nb64, 256, 0, stream>>>(x, w1abp, Xab, N);
            hipMemsetAsync(Acc, 0, (size_t)N * C_FEAT * 4, stream);
            edge_pass2<<<eb2, 256, 0, stream>>>(Xab, ea_s, ei_s, ej_s, w1cp, be1, Acc, E);
            node_fin<<<nb64, 256, 0, stream>>>(x, Acc, w2p, be2, hist, bias, out, N, 0);
            // step 2: out = h1 + (sum relu)@We2 + deg*be2 + bias
            gemm1<<<nb64, 256, 0, stream>>>(out, w1abp, Xab, N);
            hipMemsetAsync(Acc, 0, (size_t)N * C_FEAT * 4, stream);
            edge_pass2<<<eb2, 256, 0, stream>>>(Xab, ea_s, ei_s, ej_s, w1cp, be1, Acc, E);
            node_fin<<<nb64, 256, 0, stream>>>(out, Acc, w2p, be2, hist, bias, out, N, 1);
        } else {
            // previous main path
            gemm1<<<nb64, 256, 0, stream>>>(x, w1abp, Xab, N);
            copy_f4<<<cb, 256, 0, stream>>>((const float4*)x, (float4*)out, n4);
            edge_pass<<<eb2, 256, 0, stream>>>(Xab, ea_s, ei_s, ej_s, w1cp, be1, w2p, be2, out, E);
            gemm1<<<nb64, 256, 0, stream>>>(out, w1abp, Xab, N);
            bias_copy<<<cb, 256, 0, stream>>>((const float4*)out, bias, (float4*)out, n4);
            edge_pass<<<eb2, 256, 0, stream>>>(Xab, ea_s, ei_s, ej_s, w1cp, be1, w2p, be2, out, E);
        }
    } else {
        // round-1 known-good fallback
        const int eb = (E + 63) / 64;
        float* bufA = (float*)d_ws;
        short* w1p  = (short*)((char*)d_ws + (size_t)N * C_FEAT * sizeof(float));
        short* w2p  = w1p + K1 * C_FEAT;
        prep_w_r1<<<144, 256, 0, stream>>>(We1, We2, w1p, w2p);
        copy_f4<<<cb, 256, 0, stream>>>((const float4*)x, (float4*)bufA, n4);
        edge_mlp_r1<<<eb, 256, 0, stream>>>(x, bufA, ei, ej, ea, w1p, be1, w2p, be2, E);
        bias_copy<<<cb, 256, 0, stream>>>((const float4*)bufA, bias, (float4*)out, n4);
        edge_mlp_r1<<<eb, 256, 0, stream>>>(bufA, out, ei, ej, ea, w1p, be1, w2p, be2, E);
    }
}

// Round 3
// 542.937 us; speedup vs baseline: 2.6906x; 1.0451x over previous
//
#include <hip/hip_runtime.h>

#define C_FEAT 128
#define C_EDGE 32
#define K1 288

typedef __attribute__((ext_vector_type(8))) short bf16x8;
typedef __attribute__((ext_vector_type(4))) float f32x4;

__device__ __forceinline__ short f2bf(float x) {
    union { float f; unsigned u; } v; v.f = x;
    unsigned r = v.u + 0x7fffu + ((v.u >> 16) & 1u);   // RTN-even
    return (short)(r >> 16);
}
__device__ __forceinline__ float b2f(short s) {
    union { float f; unsigned u; } v; v.u = ((unsigned)(unsigned short)s) << 16;
    return v.f;
}
__device__ __forceinline__ bf16x8 cvt8(float4 a, float4 b) {
    bf16x8 r;
    r[0] = f2bf(a.x); r[1] = f2bf(a.y); r[2] = f2bf(a.z); r[3] = f2bf(a.w);
    r[4] = f2bf(b.x); r[5] = f2bf(b.y); r[6] = f2bf(b.z); r[7] = f2bf(b.w);
    return r;
}

// ---------------- weight packing ----------------
// B-fragment layout: wp[((k>>3)*F + f)*8 + (k&7)] -> 8 consecutive k for fixed
// f is one 16B load per lane.
__global__ void prep_w2(const float* __restrict__ We1, const float* __restrict__ We2,
                        short* __restrict__ w1abp, short* __restrict__ w1cp,
                        short* __restrict__ w2p) {
    int idx = blockIdx.x * 256 + threadIdx.x;
    if (idx < 128 * 256) {              // [W1a | W1b]: K=128, F=256
        int k = idx >> 8, f = idx & 255;
        float v = (f < 128) ? We1[k * 128 + f] : We1[(128 + k) * 128 + (f - 128)];
        w1abp[(((k >> 3) * 256 + f) << 3) + (k & 7)] = f2bf(v);
    }
    if (idx < 32 * 128) {               // W1c: K=32, F=128
        int k = idx >> 7, f = idx & 127;
        w1cp[(((k >> 3) * 128 + f) << 3) + (k & 7)] = f2bf(We1[(256 + k) * 128 + f]);
    }
    if (idx < 128 * 128) {              // We2
        int k = idx >> 7, f = idx & 127;
        w2p[(((k >> 3) * 128 + f) << 3) + (k & 7)] = f2bf(We2[k * 128 + f]);
    }
}

// ---------------- counting sort by ej (hist zeroed via memsetAsync) -------
__global__ void k_hist(const int* __restrict__ ej, int* __restrict__ hist, int E) {
    int e = blockIdx.x * 256 + threadIdx.x;
    if (e < E) atomicAdd(&hist[ej[e]], 1);
}
__global__ void k_red(const int* __restrict__ hist, int* __restrict__ part, int N) {
    __shared__ int s[512];
    int t = threadIdx.x, i = blockIdx.x * 512 + t;
    s[t] = i < N ? hist[i] : 0;
    __syncthreads();
    for (int o = 256; o > 0; o >>= 1) {
        if (t < o) s[t] += s[t + o];
        __syncthreads();
    }
    if (t == 0) part[blockIdx.x] = s[0];
}
// parallel exclusive scan of up to 1024 partials in one block (nb=196 here);
// serial fallback only if nb > 1024.
__global__ void k_scanpart(int* __restrict__ part, int nb) {
    __shared__ int s[1024];
    int t = threadIdx.x;
    if (nb <= 1024) {
        int v = t < nb ? part[t] : 0;
        s[t] = v;
        __syncthreads();
        for (int o = 1; o < 1024; o <<= 1) {
            int x = (t >= o) ? s[t - o] : 0;
            __syncthreads();
            s[t] += x;
            __syncthreads();
        }
        if (t < nb) part[t] = s[t] - v;   // exclusive
    } else if (t == 0) {
        int a = 0;
        for (int i = 0; i < nb; ++i) { int v = part[i]; part[i] = a; a += v; }
    }
}
__global__ void k_scanblk(const int* __restrict__ hist, const int* __restrict__ part,
                          int* __restrict__ woff, int N) {
    __shared__ int s[512];
    int t = threadIdx.x, i = blockIdx.x * 512 + t;
    int v = i < N ? hist[i] : 0;
    s[t] = v;
    __syncthreads();
    for (int o = 1; o < 512; o <<= 1) {
        int x = (t >= o) ? s[t - o] : 0;
        __syncthreads();
        s[t] += x;
        __syncthreads();
    }
    if (i < N) woff[i] = part[blockIdx.x] + s[t] - v;   // exclusive
}
// permute edges into ej-sorted order; fuse ea gather+bf16 convert.
__global__ void k_perm(const int* __restrict__ ei, const int* __restrict__ ej,
                       const float* __restrict__ ea, int* __restrict__ woff,
                       int* __restrict__ ei_s, int* __restrict__ ej_s,
                       short* __restrict__ ea_s, int E) {
    int e = blockIdx.x * 256 + threadIdx.x;
    if (e < E) {
        int t = ej[e];
        int pos = atomicAdd(&woff[t], 1);
        ei_s[pos] = ei[e];
        ej_s[pos] = t;
        const float4* src = (const float4*)(ea + (size_t)e * C_EDGE);
        short* dst = ea_s + (size_t)pos * C_EDGE;
#pragma unroll
        for (int c = 0; c < 4; ++c) {
            float4 a0 = src[2 * c], a1 = src[2 * c + 1];
            bf16x8 v = cvt8(a0, a1);
            *(bf16x8*)(dst + c * 8) = v;
        }
    }
}

// ---------------- Xab = h @ [W1a|W1b]  (N x 256, bf16) ----------------
__global__ __launch_bounds__(256) void gemm1(const float* __restrict__ h,
                                             const short* __restrict__ w1abp,
                                             short* __restrict__ Xab, int N) {
    const int tid = threadIdx.x, wave = tid >> 6, lane = tid & 63;
    const int l15 = lane & 15, q = lane >> 4;
    const int nbase = blockIdx.x * 64 + wave * 16;
    const int nr = nbase + l15;
    const int nrc = nr < N ? nr : N - 1;
    f32x4 acc[16];
#pragma unroll
    for (int nt = 0; nt < 16; ++nt) acc[nt] = (f32x4){0.f, 0.f, 0.f, 0.f};
#pragma unroll
    for (int c = 0; c < 4; ++c) {
        const float* asrc = h + (size_t)nrc * C_FEAT + c * 32 + q * 8;
        float4 a0 = ((const float4*)asrc)[0];
        float4 a1 = ((const float4*)asrc)[1];
        bf16x8 af = cvt8(a0, a1);
        const short* bb = w1abp + ((c * 4 + q) * 256) * 8;
#pragma unroll
        for (int nt = 0; nt < 16; ++nt) {
            bf16x8 bf = *(const bf16x8*)(bb + (nt * 16 + l15) * 8);
            acc[nt] = __builtin_amdgcn_mfma_f32_16x16x32_bf16(af, bf, acc[nt], 0, 0, 0);
        }
    }
#pragma unroll
    for (int rr = 0; rr < 4; ++rr) {
        int n = nbase + q * 4 + rr;
        if (n < N) {
#pragma unroll
            for (int nt = 0; nt < 16; ++nt) {
                Xab[(size_t)n * 256 + nt * 16 + l15] = f2bf(acc[nt][rr]);
            }
        }
    }
}

// ==================== relu-sum edge pass (no layer-2 GEMM) ================
// Linearity: sum_e(relu_e @ We2 + be2) = (sum_e relu_e) @ We2 + deg*be2.
// Phase A: z = ea@W1c + be1 via MFMA into XOR-swizzled LDS.
// Phase B (r2 post-mortem: latency-bound, VGPR=52 shows no load hoisting):
//   stage 1: 8 edges' indices via int4 vector loads,
//   stage 2: all 16 row-gathers issued back-to-back (16 outstanding VMEM),
//   stage 3: register-resident run-merge + LDS-transposed full-line atomics.
#define ZS2 128
__global__ __launch_bounds__(256) void edge_pass2(const short* __restrict__ Xab,
                                                  const short* __restrict__ ea_s,
                                                  const int* __restrict__ ei_s,
                                                  const int* __restrict__ ej_s,
                                                  const short* __restrict__ w1cp,
                                                  const float* __restrict__ be1,
                                                  float* __restrict__ Acc, int E) {
    __shared__ short Z[4][2][16 * ZS2];   // 32 KB
    __shared__ float S[4][4][128];        // 8 KB flush-transpose scratch
    const int tid = threadIdx.x, wave = tid >> 6, lane = tid & 63;
    const int l15 = lane & 15, q = lane >> 4;
    const int base = blockIdx.x * 128 + wave * 32;

    // ---- phase A: z for this wave's 32 edges ----
#pragma unroll
    for (int t = 0; t < 2; ++t) {
        int eg = base + t * 16 + l15;
        int egc = eg < E ? eg : E - 1;
        bf16x8 af = *(const bf16x8*)(ea_s + (size_t)egc * C_EDGE + q * 8);
        f32x4 accP[8];
#pragma unroll
        for (int nt = 0; nt < 8; ++nt) {
            bf16x8 bf = *(const bf16x8*)(w1cp + ((q * C_FEAT + nt * 16 + l15) << 3));
            accP[nt] = __builtin_amdgcn_mfma_f32_16x16x32_bf16(
                af, bf, (f32x4){0.f, 0.f, 0.f, 0.f}, 0, 0, 0);
        }
        short* zw = &Z[wave][t][0];
#pragma unroll
        for (int nt = 0; nt < 8; ++nt) {
            int f = nt * 16 + l15;
            float b = be1[f];
#pragma unroll
            for (int r = 0; r < 4; ++r) {
                int row = q * 4 + r;
                // XOR-swizzle on 16B granule keeps the 8-short read contiguous.
                zw[row * ZS2 + (f ^ ((row & 7) << 3))] = f2bf(accP[nt][r] + b);
            }
        }
    }
    __syncthreads();

    // ---- phase B ----
    const int fg = lane & 15;          // feature group: floats [fg*8, fg*8+8)
    const int es = lane >> 4;          // edge stream (4 per wave)
    const int ebase = base + es * 8;
    float* scr = &S[wave][es][0];

    // stage 1: indices (consecutive; vector path except tail block)
    int nia[8], nja[8];
    if (ebase + 8 <= E) {
        int4 a0 = *(const int4*)(ei_s + ebase);
        int4 a1 = *(const int4*)(ei_s + ebase + 4);
        int4 b0 = *(const int4*)(ej_s + ebase);
        int4 b1 = *(const int4*)(ej_s + ebase + 4);
        nia[0] = a0.x; nia[1] = a0.y; nia[2] = a0.z; nia[3] = a0.w;
        nia[4] = a1.x; nia[5] = a1.y; nia[6] = a1.z; nia[7] = a1.w;
        nja[0] = b0.x; nja[1] = b0.y; nja[2] = b0.z; nja[3] = b0.w;
        nja[4] = b1.x; nja[5] = b1.y; nja[6] = b1.z; nja[7] = b1.w;
    } else {
#pragma unroll
        for (int i = 0; i < 8; ++i) {
            int ec = (ebase + i) < E ? (ebase + i) : E - 1;
            nia[i] = ei_s[ec];
            nja[i] = ej_s[ec];
        }
    }

    // stage 2: all 16 row-gathers in flight at once
    bf16x8 xa[8], xb[8];
#pragma unroll
    for (int i = 0; i < 8; ++i) {
        xa[i] = *(const bf16x8*)(Xab + (size_t)nia[i] * 256 + fg * 8);
        xb[i] = *(const bf16x8*)(Xab + (size_t)nja[i] * 256 + 128 + fg * 8);
    }

    // stage 3: relu + run-merged line-coalesced scatter
    float vs[8];
    int cur = -1;
#pragma unroll
    for (int i = 0; i < 8; ++i) {
        int e = ebase + i;
        int eo = es * 8 + i;
        int r = eo & 15;
        bf16x8 zz = *(const bf16x8*)(&Z[wave][eo >> 4][r * ZS2 + ((fg ^ (r & 7)) << 3)]);
        if (e < E) {
            if (nja[i] != cur) {
                if (cur >= 0) {
                    // transpose through LDS, then full-line atomics
                    *(f32x4*)(scr + fg * 8)     = (f32x4){vs[0], vs[1], vs[2], vs[3]};
                    *(f32x4*)(scr + fg * 8 + 4) = (f32x4){vs[4], vs[5], vs[6], vs[7]};
                    __builtin_amdgcn_wave_barrier();
                    float* dst = Acc + (size_t)cur * C_FEAT;
#pragma unroll
                    for (int j = 0; j < 8; ++j)
                        unsafeAtomicAdd(dst + j * 16 + fg, scr[j * 16 + fg]);
                    __builtin_amdgcn_wave_barrier();
                }
                cur = nja[i];
#pragma unroll
                for (int j = 0; j < 8; ++j) vs[j] = 0.f;
            }
#pragma unroll
            for (int j = 0; j < 8; ++j) {
                float v = b2f(xa[i][j]) + b2f(xb[i][j]) + b2f(zz[j]);
                vs[j] += v > 0.f ? v : 0.f;
            }
        }
    }
    if (cur >= 0) {
        *(f32x4*)(scr + fg * 8)     = (f32x4){vs[0], vs[1], vs[2], vs[3]};
        *(f32x4*)(scr + fg * 8 + 4) = (f32x4){vs[4], vs[5], vs[6], vs[7]};
        __builtin_amdgcn_wave_barrier();
        float* dst = Acc + (size_t)cur * C_FEAT;
#pragma unroll
        for (int j = 0; j < 8; ++j)
            unsafeAtomicAdd(dst + j * 16 + fg, scr[j * 16 + fg]);
    }
}

// ---- node finalize: out = prevh + Acc@We2 + deg*be2 (+bias on last step) ----
__global__ __launch_bounds__(256) void node_fin(const float* __restrict__ prevh,
                                                const float* __restrict__ Acc,
                                                const short* __restrict__ w2p,
                                                const float* __restrict__ be2,
                                                const int* __restrict__ deg,
                                                const float* __restrict__ bias,
                                                float* __restrict__ out,
                                                int N, int addBias) {
    const int tid = threadIdx.x, wave = tid >> 6, lane = tid & 63;
    const int l15 = lane & 15, q = lane >> 4;
    const int nbase = blockIdx.x * 64 + wave * 16;
    const int nr = nbase + l15;
    const int nrc = nr < N ? nr : N - 1;
    f32x4 acc[8];
#pragma unroll
    for (int nt = 0; nt < 8; ++nt) acc[nt] = (f32x4){0.f, 0.f, 0.f, 0.f};
#pragma unroll
    for (int c = 0; c < 4; ++c) {
        const float* asrc = Acc + (size_t)nrc * C_FEAT + c * 32 + q * 8;
        float4 a0 = ((const float4*)asrc)[0];
        float4 a1 = ((const float4*)asrc)[1];
        bf16x8 af = cvt8(a0, a1);
        const short* bb = w2p + ((c * 4 + q) * C_FEAT) * 8;
#pragma unroll
        for (int nt = 0; nt < 8; ++nt) {
            bf16x8 bf = *(const bf16x8*)(bb + (nt * 16 + l15) * 8);
            acc[nt] = __builtin_amdgcn_mfma_f32_16x16x32_bf16(af, bf, acc[nt], 0, 0, 0);
        }
    }
    float dv[4];
#pragma unroll
    for (int r = 0; r < 4; ++r) {
        int n = nbase + q * 4 + r;
        dv[r] = n < N ? (float)deg[n] : 0.f;
    }
#pragma unroll
    for (int nt = 0; nt < 8; ++nt) {
        int f = nt * 16 + l15;
        float b2 = be2[f];
        float bi = addBias ? bias[f] : 0.f;
#pragma unroll
        for (int r = 0; r < 4; ++r) {
            int n = nbase + q * 4 + r;
            if (n < N) {
                out[(size_t)n * C_FEAT + f] =
                    prevh[(size_t)n * C_FEAT + f] + acc[nt][r] + dv[r] * b2 + bi;
            }
        }
    }
}

// ==================== previous main path (mid-size fallback) ===============
#define ZSTRIDE 136
__global__ __launch_bounds__(256) void edge_pass(const short* __restrict__ Xab,
                                                 const short* __restrict__ ea_s,
                                                 const int* __restrict__ ei_s,
                                                 const int* __restrict__ ej_s,
                                                 const short* __restrict__ w1cp,
                                                 const float* __restrict__ be1,
                                                 const short* __restrict__ w2p,
                                                 const float* __restrict__ be2,
                                                 float* __restrict__ hdst, int E) {
    __shared__ short Z[4][2][16 * ZSTRIDE];
    const int tid = threadIdx.x, wave = tid >> 6, lane = tid & 63;
    const int l15 = lane & 15, q = lane >> 4;
    const int base = blockIdx.x * 128 + wave * 32;

    int ni[2], nj[2], egc[2];
#pragma unroll
    for (int t = 0; t < 2; ++t) {
        int eg = base + t * 16 + l15;
        egc[t] = eg < E ? eg : E - 1;
        ni[t] = ei_s[egc[t]];
        nj[t] = ej_s[egc[t]];
    }
#pragma unroll
    for (int t = 0; t < 2; ++t) {
        bf16x8 af = *(const bf16x8*)(ea_s + (size_t)egc[t] * C_EDGE + q * 8);
        f32x4 accP[8];
#pragma unroll
        for (int nt = 0; nt < 8; ++nt) {
            bf16x8 bf = *(const bf16x8*)(w1cp + ((q * C_FEAT + nt * 16 + l15) << 3));
            accP[nt] = __builtin_amdgcn_mfma_f32_16x16x32_bf16(
                af, bf, (f32x4){0.f, 0.f, 0.f, 0.f}, 0, 0, 0);
        }
        short* zw = &Z[wave][t][0];
#pragma unroll
        for (int nt = 0; nt < 8; ++nt) {
            int f = nt * 16 + l15;
            float b = be1[f];
#pragma unroll
            for (int r = 0; r < 4; ++r) {
                zw[(q * 4 + r) * ZSTRIDE + f] = f2bf(accP[nt][r] + b);
            }
        }
    }
    __syncthreads();

    f32x4 acc[2][8];
#pragma unroll
    for (int t = 0; t < 2; ++t)
#pragma unroll
        for (int nt = 0; nt < 8; ++nt) acc[t][nt] = (f32x4){0.f, 0.f, 0.f, 0.f};
#pragma unroll
    for (int c = 0; c < 4; ++c) {
        bf16x8 bfr[8];
        const short* bb = w2p + ((c * 4 + q) * C_FEAT) * 8;
#pragma unroll
        for (int nt = 0; nt < 8; ++nt)
            bfr[nt] = *(const bf16x8*)(bb + (nt * 16 + l15) * 8);
#pragma unroll
        for (int t = 0; t < 2; ++t) {
            bf16x8 xa = *(const bf16x8*)(Xab + (size_t)ni[t] * 256 + c * 32 + q * 8);
            bf16x8 xb = *(const bf16x8*)(Xab + (size_t)nj[t] * 256 + 128 + c * 32 + q * 8);
            bf16x8 zz = *(const bf16x8*)(&Z[wave][t][l15 * ZSTRIDE + c * 32 + q * 8]);
            bf16x8 af;
#pragma unroll
            for (int j = 0; j < 8; ++j) {
                float z = b2f(xa[j]) + b2f(xb[j]) + b2f(zz[j]);
                af[j] = f2bf(z > 0.f ? z : 0.f);
            }
#pragma unroll
            for (int nt = 0; nt < 8; ++nt)
                acc[t][nt] = __builtin_amdgcn_mfma_f32_16x16x32_bf16(af, bfr[nt],
                                                                     acc[t][nt], 0, 0, 0);
        }
    }
    float b2v[8];
#pragma unroll
    for (int nt = 0; nt < 8; ++nt) b2v[nt] = be2[nt * 16 + l15];
#pragma unroll
    for (int t = 0; t < 2; ++t) {
        int cur = -1;
        float vs[8];
#pragma unroll
        for (int rr = 0; rr < 4; ++rr) {
            int e = base + t * 16 + q * 4 + rr;
            if (e < E) {
                int tn = ej_s[e];
                if (tn == cur) {
#pragma unroll
                    for (int nt = 0; nt < 8; ++nt) vs[nt] += acc[t][nt][rr] + b2v[nt];
                } else {
                    if (cur >= 0) {
                        float* dst = hdst + (size_t)cur * C_FEAT;
#pragma unroll
                        for (int nt = 0; nt < 8; ++nt)
                            unsafeAtomicAdd(dst + nt * 16 + l15, vs[nt]);
                    }
                    cur = tn;
#pragma unroll
                    for (int nt = 0; nt < 8; ++nt) vs[nt] = acc[t][nt][rr] + b2v[nt];
                }
            }
        }
        if (cur >= 0) {
            float* dst = hdst + (size_t)cur * C_FEAT;
#pragma unroll
            for (int nt = 0; nt < 8; ++nt)
                unsafeAtomicAdd(dst + nt * 16 + l15, vs[nt]);
        }
    }
}

// ---------------- elementwise helpers ----------------
__global__ void copy_f4(const float4* __restrict__ s, float4* __restrict__ d, int n4) {
    int i = blockIdx.x * 256 + threadIdx.x;
    if (i < n4) d[i] = s[i];
}
__global__ void bias_copy(const float4* __restrict__ s, const float* __restrict__ bias,
                          float4* __restrict__ d, int n4) {
    int i = blockIdx.x * 256 + threadIdx.x;
    if (i < n4) {
        float4 v = s[i];
        float4 b = ((const float4*)bias)[i & 31];
        d[i] = make_float4(v.x + b.x, v.y + b.y, v.z + b.z, v.w + b.w);
    }
}

// ================= round-1 fallback path (known-good) =================
__global__ void prep_w_r1(const float* __restrict__ W1, const float* __restrict__ W2,
                          short* __restrict__ w1p, short* __restrict__ w2p) {
    int idx = blockIdx.x * 256 + threadIdx.x;
    if (idx < K1 * C_FEAT) {
        int k = idx >> 7, f = idx & 127;
        w1p[(((k >> 3) * C_FEAT + f) << 3) + (k & 7)] = f2bf(W1[idx]);
    }
    if (idx < C_FEAT * C_FEAT) {
        int k = idx >> 7, f = idx & 127;
        w2p[(((k >> 3) * C_FEAT + f) << 3) + (k & 7)] = f2bf(W2[idx]);
    }
}
__global__ __launch_bounds__(256) void edge_mlp_r1(
    const float* __restrict__ h, float* __restrict__ hdst,
    const int* __restrict__ ei, const int* __restrict__ ej,
    const float* __restrict__ ea,
    const short* __restrict__ w1p, const float* __restrict__ be1,
    const short* __restrict__ w2p, const float* __restrict__ be2, int E) {
    __shared__ short Hs[64][136];
    const int tid = threadIdx.x, wave = tid >> 6, lane = tid & 63;
    const int l15 = lane & 15, q = lane >> 4;
    const int ewave = blockIdx.x * 64 + wave * 16;
    const int eg = ewave + l15;
    const int egc = eg < E ? eg : E - 1;
    const int ni = ei[egc], nj = ej[egc];
    f32x4 acc[8];
#pragma unroll
    for (int nt = 0; nt < 8; ++nt) acc[nt] = (f32x4){0.f, 0.f, 0.f, 0.f};
#pragma unroll
    for (int c = 0; c < 9; ++c) {
        const float* asrc;
        if (c < 4)      asrc = h + (size_t)ni * C_FEAT + c * 32 + q * 8;
        else if (c < 8) asrc = h + (size_t)nj * C_FEAT + (c - 4) * 32 + q * 8;
        else            asrc = ea + (size_t)egc * C_EDGE + q * 8;
        float4 a0 = ((const float4*)asrc)[0];
        float4 a1 = ((const float4*)asrc)[1];
        bf16x8 af = cvt8(a0, a1);
        const short* bb = w1p + ((c * 4 + q) * C_FEAT) * 8;
#pragma unroll
        for (int nt = 0; nt < 8; ++nt) {
            bf16x8 bf = *(const bf16x8*)(bb + (nt * 16 + l15) * 8);
            acc[nt] = __builtin_amdgcn_mfma_f32_16x16x32_bf16(af, bf, acc[nt], 0, 0, 0);
        }
    }
#pragma unroll
    for (int nt = 0; nt < 8; ++nt) {
        int f = nt * 16 + l15;
        float b = be1[f];
#pragma unroll
        for (int r = 0; r < 4; ++r) {
            float v = acc[nt][r] + b;
            Hs[wave * 16 + q * 4 + r][f] = f2bf(v > 0.f ? v : 0.f);
        }
    }
    __syncthreads();
    f32x4 acc2[8];
#pragma unroll
    for (int nt = 0; nt < 8; ++nt) acc2[nt] = (f32x4){0.f, 0.f, 0.f, 0.f};
#pragma unroll
    for (int c = 0; c < 4; ++c) {
        bf16x8 af = *(const bf16x8*)(&Hs[wave * 16 + l15][c * 32 + q * 8]);
        const short* bb = w2p + ((c * 4 + q) * C_FEAT) * 8;
#pragma unroll
        for (int nt = 0; nt < 8; ++nt) {
            bf16x8 bf = *(const bf16x8*)(bb + (nt * 16 + l15) * 8);
            acc2[nt] = __builtin_amdgcn_mfma_f32_16x16x32_bf16(af, bf, acc2[nt], 0, 0, 0);
        }
    }
    float b2v[8];
#pragma unroll
    for (int nt = 0; nt < 8; ++nt) b2v[nt] = be2[nt * 16 + l15];
#pragma unroll
    for (int r = 0; r < 4; ++r) {
        int e = ewave + q * 4 + r;
        if (e < E) {
            int tn = ej[e];
            float* dst = hdst + (size_t)tn * C_FEAT;
#pragma unroll
            for (int nt = 0; nt < 8; ++nt)
                unsafeAtomicAdd(dst + nt * 16 + l15, acc2[nt][r] + b2v[nt]);
        }
    }
}

static inline size_t al256(size_t x) { return (x + 255) & ~(size_t)255; }

extern "C" void kernel_launch(void* const* d_in, const int* in_sizes, int n_in,
                              void* d_out, int out_size, void* d_ws, size_t ws_size,
                              hipStream_t stream) {
    const float* x    = (const float*)d_in[0];
    const int*   eidx = (const int*)  d_in[1];
    const float* ea   = (const float*)d_in[2];
    const float* We1  = (const float*)d_in[3];
    const float* be1  = (const float*)d_in[4];
    const float* We2  = (const float*)d_in[5];
    const float* be2  = (const float*)d_in[6];
    const float* bias = (const float*)d_in[7];
    float* out = (float*)d_out;

    const int E = in_sizes[1] / 2;
    const int N = in_sizes[0] / C_FEAT;
    const int* ei = eidx;
    const int* ej = eidx + E;

    const int n4 = N * C_FEAT / 4;
    const int cb = (n4 + 255) / 256;
    const int eb2 = (E + 127) / 128;
    const int nb64 = (N + 63) / 64;

    // ---- workspace layout ----
    size_t off = 0;
    size_t o_w1abp = off; off = al256(off + (size_t)128 * 256 * 2);
    size_t o_w1cp  = off; off = al256(off + (size_t)32 * 128 * 2);
    size_t o_w2p   = off; off = al256(off + (size_t)128 * 128 * 2);
    size_t o_hist  = off; off = al256(off + (size_t)N * 4);
    size_t o_part  = off; off = al256(off + (size_t)4096);
    size_t o_woff  = off; off = al256(off + (size_t)N * 4);
    size_t o_eis   = off; off = al256(off + (size_t)E * 4);
    size_t o_ejs   = off; off = al256(off + (size_t)E * 4);
    size_t o_eas   = off; off = al256(off + (size_t)E * C_EDGE * 2);
    size_t o_xab   = off; off = al256(off + (size_t)N * 256 * 2);
    const size_t need_old = off;
    size_t o_acc   = off; off = al256(off + (size_t)N * C_FEAT * 4);
    const size_t need_new = off;

    if (ws_size >= need_old) {
        char* ws = (char*)d_ws;
        short* w1abp = (short*)(ws + o_w1abp);
        short* w1cp  = (short*)(ws + o_w1cp);
        short* w2p   = (short*)(ws + o_w2p);
        int* hist    = (int*)(ws + o_hist);
        int* part    = (int*)(ws + o_part);
        int* woff    = (int*)(ws + o_woff);
        int* ei_s    = (int*)(ws + o_eis);
        int* ej_s    = (int*)(ws + o_ejs);
        short* ea_s  = (short*)(ws + o_eas);
        short* Xab   = (short*)(ws + o_xab);

        const int nbScan = (N + 511) / 512;

        prep_w2<<<128, 256, 0, stream>>>(We1, We2, w1abp, w1cp, w2p);
        // counting sort by ej (+ fused ea permute/convert); hist survives as deg
        hipMemsetAsync(hist, 0, (size_t)N * 4, stream);
        k_hist<<<(E + 255) / 256, 256, 0, stream>>>(ej, hist, E);
        k_red<<<nbScan, 512, 0, stream>>>(hist, part, N);
        k_scanpart<<<1, 1024, 0, stream>>>(part, nbScan);
        k_scanblk<<<nbScan, 512, 0, stream>>>(hist, part, woff, N);
        k_perm<<<(E + 255) / 256, 256, 0, stream>>>(ei, ej, ea, woff, ei_s, ej_s, ea_s, E);

        if (ws_size >= need_new) {
            float* Acc = (float*)(ws + o_acc);
            // step 1: out = x + (sum relu)@We2 + deg*be2
            gemm1<<<nb64, 256, 0, stream>>>(x, w1abp, Xab, N);
            hipMemsetAsync(Acc, 0, (size_t)N * C_FEAT * 4, stream);
            edge_pass2<<<eb2, 256, 0, stream>>>(Xab, ea_s, ei_s, ej_s, w1cp, be1, Acc, E);
            node_fin<<<nb64, 256, 0, stream>>>(x, Acc, w2p, be2, hist, bias, out, N, 0);
            // step 2: out = h1 + (sum relu)@We2 + deg*be2 + bias
            gemm1<<<nb64, 256, 0, stream>>>(out, w1abp, Xab, N);
            hipMemsetAsync(Acc, 0, (size_t)N * C_FEAT * 4, stream);
            edge_pass2<<<eb2, 256, 0, stream>>>(Xab, ea_s, ei_s, ej_s, w1cp, be1, Acc, E);
            node_fin<<<nb64, 256, 0, stream>>>(out, Acc, w2p, be2, hist, bias, out, N, 1);
        } else {
            // previous main path
            gemm1<<<nb64, 256, 0, stream>>>(x, w1abp, Xab, N);
            copy_f4<<<cb, 256, 0, stream>>>((const float4*)x, (float4*)out, n4);
            edge_pass<<<eb2, 256, 0, stream>>>(Xab, ea_s, ei_s, ej_s, w1cp, be1, w2p, be2, out, E);
            gemm1<<<nb64, 256, 0, stream>>>(out, w1abp, Xab, N);
            bias_copy<<<cb, 256, 0, stream>>>((const float4*)out, bias, (float4*)out, n4);
            edge_pass<<<eb2, 256, 0, stream>>>(Xab, ea_s, ei_s, ej_s, w1cp, be1, w2p, be2, out, E);
        }
    } else {
        // round-1 known-good fallback
        const int eb = (E + 63) / 64;
        float* bufA = (float*)d_ws;
        short* w1p  = (short*)((char*)d_ws + (size_t)N * C_FEAT * sizeof(float));
        short* w2p  = w1p + K1 * C_FEAT;
        prep_w_r1<<<144, 256, 0, stream>>>(We1, We2, w1p, w2p);
        copy_f4<<<cb, 256, 0, stream>>>((const float4*)x, (float4*)bufA, n4);
        edge_mlp_r1<<<eb, 256, 0, stream>>>(x, bufA, ei, ej, ea, w1p, be1, w2p, be2, E);
        bias_copy<<<cb, 256, 0, stream>>>((const float4*)bufA, bias, (float4*)out, n4);
        edge_mlp_r1<<<eb, 256, 0, stream>>>(bufA, out, ei, ej, ea, w1p, be1, w2p, be2, E);
    }
}

// Round 4
// 528.775 us; speedup vs baseline: 2.7627x; 1.0268x over previous
//
#include <hip/hip_runtime.h>

#define C_FEAT 128
#define C_EDGE 32
#define K1 288

typedef __attribute__((ext_vector_type(8))) short bf16x8;
typedef __attribute__((ext_vector_type(4))) float f32x4;

__device__ __forceinline__ short f2bf(float x) {
    union { float f; unsigned u; } v; v.f = x;
    unsigned r = v.u + 0x7fffu + ((v.u >> 16) & 1u);   // RTN-even
    return (short)(r >> 16);
}
__device__ __forceinline__ float b2f(short s) {
    union { float f; unsigned u; } v; v.u = ((unsigned)(unsigned short)s) << 16;
    return v.f;
}
__device__ __forceinline__ bf16x8 cvt8(float4 a, float4 b) {
    bf16x8 r;
    r[0] = f2bf(a.x); r[1] = f2bf(a.y); r[2] = f2bf(a.z); r[3] = f2bf(a.w);
    r[4] = f2bf(b.x); r[5] = f2bf(b.y); r[6] = f2bf(b.z); r[7] = f2bf(b.w);
    return r;
}

// ---------------- weight packing ----------------
// B-fragment layout: wp[((k>>3)*F + f)*8 + (k&7)] -> 8 consecutive k for fixed
// f is one 16B load per lane.
__global__ void prep_w2(const float* __restrict__ We1, const float* __restrict__ We2,
                        short* __restrict__ w1abp, short* __restrict__ w1cp,
                        short* __restrict__ w2p) {
    int idx = blockIdx.x * 256 + threadIdx.x;
    if (idx < 128 * 256) {              // [W1a | W1b]: K=128, F=256
        int k = idx >> 8, f = idx & 255;
        float v = (f < 128) ? We1[k * 128 + f] : We1[(128 + k) * 128 + (f - 128)];
        w1abp[(((k >> 3) * 256 + f) << 3) + (k & 7)] = f2bf(v);
    }
    if (idx < 32 * 128) {               // W1c: K=32, F=128
        int k = idx >> 7, f = idx & 127;
        w1cp[(((k >> 3) * 128 + f) << 3) + (k & 7)] = f2bf(We1[(256 + k) * 128 + f]);
    }
    if (idx < 128 * 128) {              // We2
        int k = idx >> 7, f = idx & 127;
        w2p[(((k >> 3) * 128 + f) << 3) + (k & 7)] = f2bf(We2[k * 128 + f]);
    }
}

// ---------------- counting sort by ej (hist zeroed via memsetAsync) -------
__global__ void k_hist(const int* __restrict__ ej, int* __restrict__ hist, int E) {
    int e = blockIdx.x * 256 + threadIdx.x;
    if (e < E) atomicAdd(&hist[ej[e]], 1);
}
__global__ void k_red(const int* __restrict__ hist, int* __restrict__ part, int N) {
    __shared__ int s[512];
    int t = threadIdx.x, i = blockIdx.x * 512 + t;
    s[t] = i < N ? hist[i] : 0;
    __syncthreads();
    for (int o = 256; o > 0; o >>= 1) {
        if (t < o) s[t] += s[t + o];
        __syncthreads();
    }
    if (t == 0) part[blockIdx.x] = s[0];
}
// parallel exclusive scan of up to 1024 partials in one block (nb=196 here).
__global__ void k_scanpart(int* __restrict__ part, int nb) {
    __shared__ int s[1024];
    int t = threadIdx.x;
    if (nb <= 1024) {
        int v = t < nb ? part[t] : 0;
        s[t] = v;
        __syncthreads();
        for (int o = 1; o < 1024; o <<= 1) {
            int x = (t >= o) ? s[t - o] : 0;
            __syncthreads();
            s[t] += x;
            __syncthreads();
        }
        if (t < nb) part[t] = s[t] - v;   // exclusive
    } else if (t == 0) {
        int a = 0;
        for (int i = 0; i < nb; ++i) { int v = part[i]; part[i] = a; a += v; }
    }
}
__global__ void k_scanblk(const int* __restrict__ hist, const int* __restrict__ part,
                          int* __restrict__ woff, int N) {
    __shared__ int s[512];
    int t = threadIdx.x, i = blockIdx.x * 512 + t;
    int v = i < N ? hist[i] : 0;
    s[t] = v;
    __syncthreads();
    for (int o = 1; o < 512; o <<= 1) {
        int x = (t >= o) ? s[t - o] : 0;
        __syncthreads();
        s[t] += x;
        __syncthreads();
    }
    if (i < N) woff[i] = part[blockIdx.x] + s[t] - v;   // exclusive
}
// permute edges into ej-sorted order; fuse ea gather+bf16 convert.
__global__ void k_perm(const int* __restrict__ ei, const int* __restrict__ ej,
                       const float* __restrict__ ea, int* __restrict__ woff,
                       int* __restrict__ ei_s, int* __restrict__ ej_s,
                       short* __restrict__ ea_s, int E) {
    int e = blockIdx.x * 256 + threadIdx.x;
    if (e < E) {
        int t = ej[e];
        int pos = atomicAdd(&woff[t], 1);
        ei_s[pos] = ei[e];
        ej_s[pos] = t;
        const float4* src = (const float4*)(ea + (size_t)e * C_EDGE);
        short* dst = ea_s + (size_t)pos * C_EDGE;
#pragma unroll
        for (int c = 0; c < 4; ++c) {
            float4 a0 = src[2 * c], a1 = src[2 * c + 1];
            bf16x8 v = cvt8(a0, a1);
            *(bf16x8*)(dst + c * 8) = v;
        }
    }
}

// ---------------- Xab = h @ [W1a|W1b]  (N x 256, bf16) ----------------
__global__ __launch_bounds__(256) void gemm1(const float* __restrict__ h,
                                             const short* __restrict__ w1abp,
                                             short* __restrict__ Xab, int N) {
    const int tid = threadIdx.x, wave = tid >> 6, lane = tid & 63;
    const int l15 = lane & 15, q = lane >> 4;
    const int nbase = blockIdx.x * 64 + wave * 16;
    const int nr = nbase + l15;
    const int nrc = nr < N ? nr : N - 1;
    f32x4 acc[16];
#pragma unroll
    for (int nt = 0; nt < 16; ++nt) acc[nt] = (f32x4){0.f, 0.f, 0.f, 0.f};
#pragma unroll
    for (int c = 0; c < 4; ++c) {
        const float* asrc = h + (size_t)nrc * C_FEAT + c * 32 + q * 8;
        float4 a0 = ((const float4*)asrc)[0];
        float4 a1 = ((const float4*)asrc)[1];
        bf16x8 af = cvt8(a0, a1);
        const short* bb = w1abp + ((c * 4 + q) * 256) * 8;
#pragma unroll
        for (int nt = 0; nt < 16; ++nt) {
            bf16x8 bf = *(const bf16x8*)(bb + (nt * 16 + l15) * 8);
            acc[nt] = __builtin_amdgcn_mfma_f32_16x16x32_bf16(af, bf, acc[nt], 0, 0, 0);
        }
    }
#pragma unroll
    for (int rr = 0; rr < 4; ++rr) {
        int n = nbase + q * 4 + rr;
        if (n < N) {
#pragma unroll
            for (int nt = 0; nt < 16; ++nt) {
                Xab[(size_t)n * 256 + nt * 16 + l15] = f2bf(acc[nt][rr]);
            }
        }
    }
}

// ==================== relu-sum edge pass (no layer-2 GEMM) ================
// Linearity: sum_e(relu_e @ We2 + be2) = (sum_e relu_e) @ We2 + deg*be2.
// Phase A: z = ea@W1c + be1 via MFMA into XOR-swizzled LDS.
// Phase B: stage 1 idx loads, stage 2 all 16 row-gathers, sched_barrier(0)
//          fence so the compiler CANNOT sink the gathers (r3: it did, VGPR=56),
//          stage 3 register run-merge + LDS-transposed full-line atomics.
#define ZS2 128
__global__ __launch_bounds__(256) void edge_pass2(const short* __restrict__ Xab,
                                                  const short* __restrict__ ea_s,
                                                  const int* __restrict__ ei_s,
                                                  const int* __restrict__ ej_s,
                                                  const short* __restrict__ w1cp,
                                                  const float* __restrict__ be1,
                                                  float* __restrict__ Acc, int E) {
    __shared__ short Z[4][2][16 * ZS2];   // 32 KB
    __shared__ float S[4][4][128];        // 8 KB flush-transpose scratch
    const int tid = threadIdx.x, wave = tid >> 6, lane = tid & 63;
    const int l15 = lane & 15, q = lane >> 4;
    const int base = blockIdx.x * 128 + wave * 32;

    // ---- phase A: z for this wave's 32 edges ----
#pragma unroll
    for (int t = 0; t < 2; ++t) {
        int eg = base + t * 16 + l15;
        int egc = eg < E ? eg : E - 1;
        bf16x8 af = *(const bf16x8*)(ea_s + (size_t)egc * C_EDGE + q * 8);
        f32x4 accP[8];
#pragma unroll
        for (int nt = 0; nt < 8; ++nt) {
            bf16x8 bf = *(const bf16x8*)(w1cp + ((q * C_FEAT + nt * 16 + l15) << 3));
            accP[nt] = __builtin_amdgcn_mfma_f32_16x16x32_bf16(
                af, bf, (f32x4){0.f, 0.f, 0.f, 0.f}, 0, 0, 0);
        }
        short* zw = &Z[wave][t][0];
#pragma unroll
        for (int nt = 0; nt < 8; ++nt) {
            int f = nt * 16 + l15;
            float b = be1[f];
#pragma unroll
            for (int r = 0; r < 4; ++r) {
                int row = q * 4 + r;
                // XOR-swizzle on 16B granule keeps the 8-short read contiguous.
                zw[row * ZS2 + (f ^ ((row & 7) << 3))] = f2bf(accP[nt][r] + b);
            }
        }
    }
    __syncthreads();

    // ---- phase B ----
    const int fg = lane & 15;          // feature group: floats [fg*8, fg*8+8)
    const int es = lane >> 4;          // edge stream (4 per wave)
    const int ebase = base + es * 8;
    float* scr = &S[wave][es][0];

    // stage 1: indices (consecutive; vector path except tail block)
    int nia[8], nja[8];
    if (ebase + 8 <= E) {
        int4 a0 = *(const int4*)(ei_s + ebase);
        int4 a1 = *(const int4*)(ei_s + ebase + 4);
        int4 b0 = *(const int4*)(ej_s + ebase);
        int4 b1 = *(const int4*)(ej_s + ebase + 4);
        nia[0] = a0.x; nia[1] = a0.y; nia[2] = a0.z; nia[3] = a0.w;
        nia[4] = a1.x; nia[5] = a1.y; nia[6] = a1.z; nia[7] = a1.w;
        nja[0] = b0.x; nja[1] = b0.y; nja[2] = b0.z; nja[3] = b0.w;
        nja[4] = b1.x; nja[5] = b1.y; nja[6] = b1.z; nja[7] = b1.w;
    } else {
#pragma unroll
        for (int i = 0; i < 8; ++i) {
            int ec = (ebase + i) < E ? (ebase + i) : E - 1;
            nia[i] = ei_s[ec];
            nja[i] = ej_s[ec];
        }
    }

    // stage 2: all 16 row-gathers in flight at once
    bf16x8 xa[8], xb[8];
#pragma unroll
    for (int i = 0; i < 8; ++i) {
        xa[i] = *(const bf16x8*)(Xab + (size_t)nia[i] * 256 + fg * 8);
        xb[i] = *(const bf16x8*)(Xab + (size_t)nja[i] * 256 + 128 + fg * 8);
    }
    // hard scheduling fence: no instruction may cross; gathers must all issue
    // before any stage-3 consumption -> 16 outstanding VMEM per lane.
    __builtin_amdgcn_sched_barrier(0);

    // stage 3: relu + run-merged line-coalesced scatter
    float vs[8];
    int cur = -1;
#pragma unroll
    for (int i = 0; i < 8; ++i) {
        int e = ebase + i;
        int eo = es * 8 + i;
        int r = eo & 15;
        bf16x8 zz = *(const bf16x8*)(&Z[wave][eo >> 4][r * ZS2 + ((fg ^ (r & 7)) << 3)]);
        if (e < E) {
            if (nja[i] != cur) {
                if (cur >= 0) {
                    // transpose through LDS, then full-line atomics
                    *(f32x4*)(scr + fg * 8)     = (f32x4){vs[0], vs[1], vs[2], vs[3]};
                    *(f32x4*)(scr + fg * 8 + 4) = (f32x4){vs[4], vs[5], vs[6], vs[7]};
                    __builtin_amdgcn_wave_barrier();
                    float* dst = Acc + (size_t)cur * C_FEAT;
#pragma unroll
                    for (int j = 0; j < 8; ++j)
                        unsafeAtomicAdd(dst + j * 16 + fg, scr[j * 16 + fg]);
                    __builtin_amdgcn_wave_barrier();
                }
                cur = nja[i];
#pragma unroll
                for (int j = 0; j < 8; ++j) vs[j] = 0.f;
            }
#pragma unroll
            for (int j = 0; j < 8; ++j) {
                float v = b2f(xa[i][j]) + b2f(xb[i][j]) + b2f(zz[j]);
                vs[j] += v > 0.f ? v : 0.f;
            }
        }
    }
    if (cur >= 0) {
        *(f32x4*)(scr + fg * 8)     = (f32x4){vs[0], vs[1], vs[2], vs[3]};
        *(f32x4*)(scr + fg * 8 + 4) = (f32x4){vs[4], vs[5], vs[6], vs[7]};
        __builtin_amdgcn_wave_barrier();
        float* dst = Acc + (size_t)cur * C_FEAT;
#pragma unroll
        for (int j = 0; j < 8; ++j)
            unsafeAtomicAdd(dst + j * 16 + fg, scr[j * 16 + fg]);
    }
}

// ---- node finalize: out = prevh + Acc@We2 + deg*be2 (+bias on last step) ----
__global__ __launch_bounds__(256) void node_fin(const float* __restrict__ prevh,
                                                const float* __restrict__ Acc,
                                                const short* __restrict__ w2p,
                                                const float* __restrict__ be2,
                                                const int* __restrict__ deg,
                                                const float* __restrict__ bias,
                                                float* __restrict__ out,
                                                int N, int addBias) {
    const int tid = threadIdx.x, wave = tid >> 6, lane = tid & 63;
    const int l15 = lane & 15, q = lane >> 4;
    const int nbase = blockIdx.x * 64 + wave * 16;
    const int nr = nbase + l15;
    const int nrc = nr < N ? nr : N - 1;
    f32x4 acc[8];
#pragma unroll
    for (int nt = 0; nt < 8; ++nt) acc[nt] = (f32x4){0.f, 0.f, 0.f, 0.f};
#pragma unroll
    for (int c = 0; c < 4; ++c) {
        const float* asrc = Acc + (size_t)nrc * C_FEAT + c * 32 + q * 8;
        float4 a0 = ((const float4*)asrc)[0];
        float4 a1 = ((const float4*)asrc)[1];
        bf16x8 af = cvt8(a0, a1);
        const short* bb = w2p + ((c * 4 + q) * C_FEAT) * 8;
#pragma unroll
        for (int nt = 0; nt < 8; ++nt) {
            bf16x8 bf = *(const bf16x8*)(bb + (nt * 16 + l15) * 8);
            acc[nt] = __builtin_amdgcn_mfma_f32_16x16x32_bf16(af, bf, acc[nt], 0, 0, 0);
        }
    }
    float dv[4];
#pragma unroll
    for (int r = 0; r < 4; ++r) {
        int n = nbase + q * 4 + r;
        dv[r] = n < N ? (float)deg[n] : 0.f;
    }
#pragma unroll
    for (int nt = 0; nt < 8; ++nt) {
        int f = nt * 16 + l15;
        float b2 = be2[f];
        float bi = addBias ? bias[f] : 0.f;
#pragma unroll
        for (int r = 0; r < 4; ++r) {
            int n = nbase + q * 4 + r;
            if (n < N) {
                out[(size_t)n * C_FEAT + f] =
                    prevh[(size_t)n * C_FEAT + f] + acc[nt][r] + dv[r] * b2 + bi;
            }
        }
    }
}

// ==== fused: h1 = prevh + Acc@We2 + deg*be2 ; Acc = 0 ; Xab = h1@W1ab ======
// Replaces node_fin(step1) + memset(Acc) + gemm1(step2): kills the 51MB h1
// re-read, one dispatch, and overlaps the Acc zeroing with compute.
__global__ __launch_bounds__(256) void fin_gemm(const float* __restrict__ prevh,
                                                float* __restrict__ Acc,
                                                const short* __restrict__ w2p,
                                                const float* __restrict__ be2,
                                                const int* __restrict__ deg,
                                                const short* __restrict__ w1abp,
                                                float* __restrict__ out,
                                                short* __restrict__ Xab, int N) {
    __shared__ short H[4][16 * 128];   // per-wave 16x128 bf16, XOR-swizzled
    const int tid = threadIdx.x, wave = tid >> 6, lane = tid & 63;
    const int l15 = lane & 15, q = lane >> 4;
    const int nbase = blockIdx.x * 64 + wave * 16;
    const int nr = nbase + l15;
    const int nrc = nr < N ? nr : N - 1;

    // ---- GEMM2: Acc @ We2 (+ in-place zeroing of Acc) ----
    f32x4 acc[8];
#pragma unroll
    for (int nt = 0; nt < 8; ++nt) acc[nt] = (f32x4){0.f, 0.f, 0.f, 0.f};
#pragma unroll
    for (int c = 0; c < 4; ++c) {
        float* asrc = Acc + (size_t)nrc * C_FEAT + c * 32 + q * 8;
        float4 a0 = ((const float4*)asrc)[0];
        float4 a1 = ((const float4*)asrc)[1];
        bf16x8 af = cvt8(a0, a1);
        if (nr < N) {   // guard: clamped lanes must not race the true owner
            ((float4*)asrc)[0] = make_float4(0.f, 0.f, 0.f, 0.f);
            ((float4*)asrc)[1] = make_float4(0.f, 0.f, 0.f, 0.f);
        }
        const short* bb = w2p + ((c * 4 + q) * C_FEAT) * 8;
#pragma unroll
        for (int nt = 0; nt < 8; ++nt) {
            bf16x8 bf = *(const bf16x8*)(bb + (nt * 16 + l15) * 8);
            acc[nt] = __builtin_amdgcn_mfma_f32_16x16x32_bf16(af, bf, acc[nt], 0, 0, 0);
        }
    }
    float dv[4];
#pragma unroll
    for (int r = 0; r < 4; ++r) {
        int n = nbase + q * 4 + r;
        int nc = n < N ? n : N - 1;
        dv[r] = (float)deg[nc];
    }
    // ---- h1 epilogue: write out + stage bf16(h1) into swizzled LDS ----
    short* Hw = &H[wave][0];
#pragma unroll
    for (int nt = 0; nt < 8; ++nt) {
        int f = nt * 16 + l15;
        float b2 = be2[f];
#pragma unroll
        for (int r = 0; r < 4; ++r) {
            int n = nbase + q * 4 + r;
            int nc = n < N ? n : N - 1;
            float v = prevh[(size_t)nc * C_FEAT + f] + acc[nt][r] + dv[r] * b2;
            if (n < N) out[(size_t)n * C_FEAT + f] = v;
            int row = q * 4 + r;
            Hw[row * 128 + (f ^ ((row & 7) << 3))] = f2bf(v);
        }
    }
    __syncthreads();

    // ---- GEMM1: Xab = h1 @ [W1a|W1b] ----
    f32x4 acc2[16];
#pragma unroll
    for (int nt = 0; nt < 16; ++nt) acc2[nt] = (f32x4){0.f, 0.f, 0.f, 0.f};
#pragma unroll
    for (int c = 0; c < 4; ++c) {
        int row = l15;
        bf16x8 af = *(const bf16x8*)(&Hw[row * 128 + (((c * 4 + q) ^ (row & 7)) << 3)]);
        const short* bb = w1abp + ((c * 4 + q) * 256) * 8;
#pragma unroll
        for (int nt = 0; nt < 16; ++nt) {
            bf16x8 bf = *(const bf16x8*)(bb + (nt * 16 + l15) * 8);
            acc2[nt] = __builtin_amdgcn_mfma_f32_16x16x32_bf16(af, bf, acc2[nt], 0, 0, 0);
        }
    }
#pragma unroll
    for (int rr = 0; rr < 4; ++rr) {
        int n = nbase + q * 4 + rr;
        if (n < N) {
#pragma unroll
            for (int nt = 0; nt < 16; ++nt) {
                Xab[(size_t)n * 256 + nt * 16 + l15] = f2bf(acc2[nt][rr]);
            }
        }
    }
}

// ==================== previous main path (mid-size fallback) ===============
#define ZSTRIDE 136
__global__ __launch_bounds__(256) void edge_pass(const short* __restrict__ Xab,
                                                 const short* __restrict__ ea_s,
                                                 const int* __restrict__ ei_s,
                                                 const int* __restrict__ ej_s,
                                                 const short* __restrict__ w1cp,
                                                 const float* __restrict__ be1,
                                                 const short* __restrict__ w2p,
                                                 const float* __restrict__ be2,
                                                 float* __restrict__ hdst, int E) {
    __shared__ short Z[4][2][16 * ZSTRIDE];
    const int tid = threadIdx.x, wave = tid >> 6, lane = tid & 63;
    const int l15 = lane & 15, q = lane >> 4;
    const int base = blockIdx.x * 128 + wave * 32;

    int ni[2], nj[2], egc[2];
#pragma unroll
    for (int t = 0; t < 2; ++t) {
        int eg = base + t * 16 + l15;
        egc[t] = eg < E ? eg : E - 1;
        ni[t] = ei_s[egc[t]];
        nj[t] = ej_s[egc[t]];
    }
#pragma unroll
    for (int t = 0; t < 2; ++t) {
        bf16x8 af = *(const bf16x8*)(ea_s + (size_t)egc[t] * C_EDGE + q * 8);
        f32x4 accP[8];
#pragma unroll
        for (int nt = 0; nt < 8; ++nt) {
            bf16x8 bf = *(const bf16x8*)(w1cp + ((q * C_FEAT + nt * 16 + l15) << 3));
            accP[nt] = __builtin_amdgcn_mfma_f32_16x16x32_bf16(
                af, bf, (f32x4){0.f, 0.f, 0.f, 0.f}, 0, 0, 0);
        }
        short* zw = &Z[wave][t][0];
#pragma unroll
        for (int nt = 0; nt < 8; ++nt) {
            int f = nt * 16 + l15;
            float b = be1[f];
#pragma unroll
            for (int r = 0; r < 4; ++r) {
                zw[(q * 4 + r) * ZSTRIDE + f] = f2bf(accP[nt][r] + b);
            }
        }
    }
    __syncthreads();

    f32x4 acc[2][8];
#pragma unroll
    for (int t = 0; t < 2; ++t)
#pragma unroll
        for (int nt = 0; nt < 8; ++nt) acc[t][nt] = (f32x4){0.f, 0.f, 0.f, 0.f};
#pragma unroll
    for (int c = 0; c < 4; ++c) {
        bf16x8 bfr[8];
        const short* bb = w2p + ((c * 4 + q) * C_FEAT) * 8;
#pragma unroll
        for (int nt = 0; nt < 8; ++nt)
            bfr[nt] = *(const bf16x8*)(bb + (nt * 16 + l15) * 8);
#pragma unroll
        for (int t = 0; t < 2; ++t) {
            bf16x8 xa = *(const bf16x8*)(Xab + (size_t)ni[t] * 256 + c * 32 + q * 8);
            bf16x8 xb = *(const bf16x8*)(Xab + (size_t)nj[t] * 256 + 128 + c * 32 + q * 8);
            bf16x8 zz = *(const bf16x8*)(&Z[wave][t][l15 * ZSTRIDE + c * 32 + q * 8]);
            bf16x8 af;
#pragma unroll
            for (int j = 0; j < 8; ++j) {
                float z = b2f(xa[j]) + b2f(xb[j]) + b2f(zz[j]);
                af[j] = f2bf(z > 0.f ? z : 0.f);
            }
#pragma unroll
            for (int nt = 0; nt < 8; ++nt)
                acc[t][nt] = __builtin_amdgcn_mfma_f32_16x16x32_bf16(af, bfr[nt],
                                                                     acc[t][nt], 0, 0, 0);
        }
    }
    float b2v[8];
#pragma unroll
    for (int nt = 0; nt < 8; ++nt) b2v[nt] = be2[nt * 16 + l15];
#pragma unroll
    for (int t = 0; t < 2; ++t) {
        int cur = -1;
        float vs[8];
#pragma unroll
        for (int rr = 0; rr < 4; ++rr) {
            int e = base + t * 16 + q * 4 + rr;
            if (e < E) {
                int tn = ej_s[e];
                if (tn == cur) {
#pragma unroll
                    for (int nt = 0; nt < 8; ++nt) vs[nt] += acc[t][nt][rr] + b2v[nt];
                } else {
                    if (cur >= 0) {
                        float* dst = hdst + (size_t)cur * C_FEAT;
#pragma unroll
                        for (int nt = 0; nt < 8; ++nt)
                            unsafeAtomicAdd(dst + nt * 16 + l15, vs[nt]);
                    }
                    cur = tn;
#pragma unroll
                    for (int nt = 0; nt < 8; ++nt) vs[nt] = acc[t][nt][rr] + b2v[nt];
                }
            }
        }
        if (cur >= 0) {
            float* dst = hdst + (size_t)cur * C_FEAT;
#pragma unroll
            for (int nt = 0; nt < 8; ++nt)
                unsafeAtomicAdd(dst + nt * 16 + l15, vs[nt]);
        }
    }
}

// ---------------- elementwise helpers ----------------
__global__ void copy_f4(const float4* __restrict__ s, float4* __restrict__ d, int n4) {
    int i = blockIdx.x * 256 + threadIdx.x;
    if (i < n4) d[i] = s[i];
}
__global__ void bias_copy(const float4* __restrict__ s, const float* __restrict__ bias,
                          float4* __restrict__ d, int n4) {
    int i = blockIdx.x * 256 + threadIdx.x;
    if (i < n4) {
        float4 v = s[i];
        float4 b = ((const float4*)bias)[i & 31];
        d[i] = make_float4(v.x + b.x, v.y + b.y, v.z + b.z, v.w + b.w);
    }
}

// ================= round-1 fallback path (known-good) =================
__global__ void prep_w_r1(const float* __restrict__ W1, const float* __restrict__ W2,
                          short* __restrict__ w1p, short* __restrict__ w2p) {
    int idx = blockIdx.x * 256 + threadIdx.x;
    if (idx < K1 * C_FEAT) {
        int k = idx >> 7, f = idx & 127;
        w1p[(((k >> 3) * C_FEAT + f) << 3) + (k & 7)] = f2bf(W1[idx]);
    }
    if (idx < C_FEAT * C_FEAT) {
        int k = idx >> 7, f = idx & 127;
        w2p[(((k >> 3) * C_FEAT + f) << 3) + (k & 7)] = f2bf(W2[idx]);
    }
}
__global__ __launch_bounds__(256) void edge_mlp_r1(
    const float* __restrict__ h, float* __restrict__ hdst,
    const int* __restrict__ ei, const int* __restrict__ ej,
    const float* __restrict__ ea,
    const short* __restrict__ w1p, const float* __restrict__ be1,
    const short* __restrict__ w2p, const float* __restrict__ be2, int E) {
    __shared__ short Hs[64][136];
    const int tid = threadIdx.x, wave = tid >> 6, lane = tid & 63;
    const int l15 = lane & 15, q = lane >> 4;
    const int ewave = blockIdx.x * 64 + wave * 16;
    const int eg = ewave + l15;
    const int egc = eg < E ? eg : E - 1;
    const int ni = ei[egc], nj = ej[egc];
    f32x4 acc[8];
#pragma unroll
    for (int nt = 0; nt < 8; ++nt) acc[nt] = (f32x4){0.f, 0.f, 0.f, 0.f};
#pragma unroll
    for (int c = 0; c < 9; ++c) {
        const float* asrc;
        if (c < 4)      asrc = h + (size_t)ni * C_FEAT + c * 32 + q * 8;
        else if (c < 8) asrc = h + (size_t)nj * C_FEAT + (c - 4) * 32 + q * 8;
        else            asrc = ea + (size_t)egc * C_EDGE + q * 8;
        float4 a0 = ((const float4*)asrc)[0];
        float4 a1 = ((const float4*)asrc)[1];
        bf16x8 af = cvt8(a0, a1);
        const short* bb = w1p + ((c * 4 + q) * C_FEAT) * 8;
#pragma unroll
        for (int nt = 0; nt < 8; ++nt) {
            bf16x8 bf = *(const bf16x8*)(bb + (nt * 16 + l15) * 8);
            acc[nt] = __builtin_amdgcn_mfma_f32_16x16x32_bf16(af, bf, acc[nt], 0, 0, 0);
        }
    }
#pragma unroll
    for (int nt = 0; nt < 8; ++nt) {
        int f = nt * 16 + l15;
        float b = be1[f];
#pragma unroll
        for (int r = 0; r < 4; ++r) {
            float v = acc[nt][r] + b;
            Hs[wave * 16 + q * 4 + r][f] = f2bf(v > 0.f ? v : 0.f);
        }
    }
    __syncthreads();
    f32x4 acc2[8];
#pragma unroll
    for (int nt = 0; nt < 8; ++nt) acc2[nt] = (f32x4){0.f, 0.f, 0.f, 0.f};
#pragma unroll
    for (int c = 0; c < 4; ++c) {
        bf16x8 af = *(const bf16x8*)(&Hs[wave * 16 + l15][c * 32 + q * 8]);
        const short* bb = w2p + ((c * 4 + q) * C_FEAT) * 8;
#pragma unroll
        for (int nt = 0; nt < 8; ++nt) {
            bf16x8 bf = *(const bf16x8*)(bb + (nt * 16 + l15) * 8);
            acc2[nt] = __builtin_amdgcn_mfma_f32_16x16x32_bf16(af, bf, acc2[nt], 0, 0, 0);
        }
    }
    float b2v[8];
#pragma unroll
    for (int nt = 0; nt < 8; ++nt) b2v[nt] = be2[nt * 16 + l15];
#pragma unroll
    for (int r = 0; r < 4; ++r) {
        int e = ewave + q * 4 + r;
        if (e < E) {
            int tn = ej[e];
            float* dst = hdst + (size_t)tn * C_FEAT;
#pragma unroll
            for (int nt = 0; nt < 8; ++nt)
                unsafeAtomicAdd(dst + nt * 16 + l15, acc2[nt][r] + b2v[nt]);
        }
    }
}

static inline size_t al256(size_t x) { return (x + 255) & ~(size_t)255; }

extern "C" void kernel_launch(void* const* d_in, const int* in_sizes, int n_in,
                              void* d_out, int out_size, void* d_ws, size_t ws_size,
                              hipStream_t stream) {
    const float* x    = (const float*)d_in[0];
    const int*   eidx = (const int*)  d_in[1];
    const float* ea   = (const float*)d_in[2];
    const float* We1  = (const float*)d_in[3];
    const float* be1  = (const float*)d_in[4];
    const float* We2  = (const float*)d_in[5];
    const float* be2  = (const float*)d_in[6];
    const float* bias = (const float*)d_in[7];
    float* out = (float*)d_out;

    const int E = in_sizes[1] / 2;
    const int N = in_sizes[0] / C_FEAT;
    const int* ei = eidx;
    const int* ej = eidx + E;

    const int n4 = N * C_FEAT / 4;
    const int cb = (n4 + 255) / 256;
    const int eb2 = (E + 127) / 128;
    const int nb64 = (N + 63) / 64;

    // ---- workspace layout ----
    size_t off = 0;
    size_t o_w1abp = off; off = al256(off + (size_t)128 * 256 * 2);
    size_t o_w1cp  = off; off = al256(off + (size_t)32 * 128 * 2);
    size_t o_w2p   = off; off = al256(off + (size_t)128 * 128 * 2);
    size_t o_hist  = off; off = al256(off + (size_t)N * 4);
    size_t o_part  = off; off = al256(off + (size_t)4096);
    size_t o_woff  = off; off = al256(off + (size_t)N * 4);
    size_t o_eis   = off; off = al256(off + (size_t)E * 4);
    size_t o_ejs   = off; off = al256(off + (size_t)E * 4);
    size_t o_eas   = off; off = al256(off + (size_t)E * C_EDGE * 2);
    size_t o_xab   = off; off = al256(off + (size_t)N * 256 * 2);
    const size_t need_old = off;
    size_t o_acc   = off; off = al256(off + (size_t)N * C_FEAT * 4);
    const size_t need_new = off;

    if (ws_size >= need_old) {
        char* ws = (char*)d_ws;
        short* w1abp = (short*)(ws + o_w1abp);
        short* w1cp  = (short*)(ws + o_w1cp);
        short* w2p   = (short*)(ws + o_w2p);
        int* hist    = (int*)(ws + o_hist);
        int* part    = (int*)(ws + o_part);
        int* woff    = (int*)(ws + o_woff);
        int* ei_s    = (int*)(ws + o_eis);
        int* ej_s    = (int*)(ws + o_ejs);
        short* ea_s  = (short*)(ws + o_eas);
        short* Xab   = (short*)(ws + o_xab);

        const int nbScan = (N + 511) / 512;

        prep_w2<<<128, 256, 0, stream>>>(We1, We2, w1abp, w1cp, w2p);
        // counting sort by ej (+ fused ea permute/convert); hist survives as deg
        hipMemsetAsync(hist, 0, (size_t)N * 4, stream);
        k_hist<<<(E + 255) / 256, 256, 0, stream>>>(ej, hist, E);
        k_red<<<nbScan, 512, 0, stream>>>(hist, part, N);
        k_scanpart<<<1, 1024, 0, stream>>>(part, nbScan);
        k_scanblk<<<nbScan, 512, 0, stream>>>(hist, part, woff, N);
        k_perm<<<(E + 255) / 256, 256, 0, stream>>>(ei, ej, ea, woff, ei_s, ej_s, ea_s, E);

        if (ws_size >= need_new) {
            float* Acc = (float*)(ws + o_acc);
            // step 1: h1 = x + (sum relu)@We2 + deg*be2
            gemm1<<<nb64, 256, 0, stream>>>(x, w1abp, Xab, N);
            hipMemsetAsync(Acc, 0, (size_t)N * C_FEAT * 4, stream);
            edge_pass2<<<eb2, 256, 0, stream>>>(Xab, ea_s, ei_s, ej_s, w1cp, be1, Acc, E);
            // fused: out=h1, Acc=0, Xab=h1@W1ab
            fin_gemm<<<nb64, 256, 0, stream>>>(x, Acc, w2p, be2, hist, w1abp, out, Xab, N);
            // step 2: out = h1 + (sum relu)@We2 + deg*be2 + bias
            edge_pass2<<<eb2, 256, 0, stream>>>(Xab, ea_s, ei_s, ej_s, w1cp, be1, Acc, E);
            node_fin<<<nb64, 256, 0, stream>>>(out, Acc, w2p, be2, hist, bias, out, N, 1);
        } else {
            // previous main path
            gemm1<<<nb64, 256, 0, stream>>>(x, w1abp, Xab, N);
            copy_f4<<<cb, 256, 0, stream>>>((const float4*)x, (float4*)out, n4);
            edge_pass<<<eb2, 256, 0, stream>>>(Xab, ea_s, ei_s, ej_s, w1cp, be1, w2p, be2, out, E);
            gemm1<<<nb64, 256, 0, stream>>>(out, w1abp, Xab, N);
            bias_copy<<<cb, 256, 0, stream>>>((const float4*)out, bias, (float4*)out, n4);
            edge_pass<<<eb2, 256, 0, stream>>>(Xab, ea_s, ei_s, ej_s, w1cp, be1, w2p, be2, out, E);
        }
    } else {
        // round-1 known-good fallback
        const int eb = (E + 63) / 64;
        float* bufA = (float*)d_ws;
        short* w1p  = (short*)((char*)d_ws + (size_t)N * C_FEAT * sizeof(float));
        short* w2p  = w1p + K1 * C_FEAT;
        prep_w_r1<<<144, 256, 0, stream>>>(We1, We2, w1p, w2p);
        copy_f4<<<cb, 256, 0, stream>>>((const float4*)x, (float4*)bufA, n4);
        edge_mlp_r1<<<eb, 256, 0, stream>>>(x, bufA, ei, ej, ea, w1p, be1, w2p, be2, E);
        bias_copy<<<cb, 256, 0, stream>>>((const float4*)bufA, bias, (float4*)out, n4);
        edge_mlp_r1<<<eb, 256, 0, stream>>>(bufA, out, ei, ej, ea, w1p, be1, w2p, be2, E);
    }
}